// Round 3
// baseline (750.435 us; speedup 1.0000x reference)
//
#include <hip/hip_runtime.h>
#include <hip/hip_bf16.h>
#include <cmath>

#define Bn 2
#define Sn 2048
#define En 2048
#define Hn 16
#define HDn 128
#define Mn (Bn*Sn)
#define NORMS2 92.33248261689366f   /* 64 * log2(e) : softmax done in base 2 */

typedef __attribute__((ext_vector_type(8))) short short8;
typedef __attribute__((ext_vector_type(4))) float f32x4;

__device__ __forceinline__ short f2bf(float x) {
    __hip_bfloat16 h = __float2bfloat16(x);
    return *reinterpret_cast<short*>(&h);
}
__device__ __forceinline__ float bf2f(short s) {
    __hip_bfloat16 h = *reinterpret_cast<__hip_bfloat16*>(&s);
    return __bfloat162float(h);
}
__device__ __forceinline__ void gl_lds16(const void* g, void* l) {
    __builtin_amdgcn_global_load_lds(
        (const __attribute__((address_space(1))) unsigned int*)g,
        (__attribute__((address_space(3))) unsigned int*)l, 16, 0, 0);
}

#if __has_builtin(__builtin_amdgcn_exp2f)
#define EXP2(x) __builtin_amdgcn_exp2f(x)
#else
#define EXP2(x) exp2f(x)
#endif

template<int CTRL>
__device__ __forceinline__ float dppf(float x) {
    int r = __builtin_amdgcn_update_dpp(0, __builtin_bit_cast(int, x), CTRL, 0xf, 0xf, true);
    return __builtin_bit_cast(float, r);
}
__device__ __forceinline__ float redmax16(float x) {
    x = fmaxf(x, dppf<0xB1>(x));   // quad_perm xor1
    x = fmaxf(x, dppf<0x4E>(x));   // quad_perm xor2
    x = fmaxf(x, dppf<0x141>(x));  // row_half_mirror xor7
    x = fmaxf(x, dppf<0x140>(x));  // row_mirror xor15
    return x;
}
__device__ __forceinline__ float redsum16(float x) {
    x += dppf<0xB1>(x);
    x += dppf<0x4E>(x);
    x += dppf<0x141>(x);
    x += dppf<0x140>(x);
    return x;
}

// ---- sin/cos tables in fp64 ----
static __global__ void rope_table_kernel(float* __restrict__ sinT, float* __restrict__ cosT) {
    int i = blockIdx.x * 256 + threadIdx.x;
    int t = i >> 6, f = i & 63;
    double inv = pow(10000.0, -(double)(2 * f) / (double)HDn);
    double ang = (double)t * inv;
    sinT[i] = (float)sin(ang);
    cosT[i] = (float)cos(ang);
}

// ---- split fp32 -> bf16 hi/lo ----
static __global__ void split_x_kernel(const float* __restrict__ X,
                                      short* __restrict__ Xhi, short* __restrict__ Xlo) {
    int i = (blockIdx.x * 256 + threadIdx.x) * 4;
    float4 x = *(const float4*)&X[i];
    short4 hi, lo;
    hi.x = f2bf(x.x); lo.x = f2bf(x.x - bf2f(hi.x));
    hi.y = f2bf(x.y); lo.y = f2bf(x.y - bf2f(hi.y));
    hi.z = f2bf(x.z); lo.z = f2bf(x.z - bf2f(hi.z));
    hi.w = f2bf(x.w); lo.w = f2bf(x.w - bf2f(hi.w));
    *(short4*)&Xhi[i] = hi;
    *(short4*)&Xlo[i] = lo;
}

// ---- mask fp32 -> bf16, pre-scaled by NORMS2 (exact for zero mask) ----
static __global__ void maskconv_kernel(const float* __restrict__ M, short* __restrict__ MB) {
    int i = (blockIdx.x * 256 + threadIdx.x) * 4;
    float4 m = *(const float4*)&M[i];
    short4 o;
    o.x = f2bf(m.x * NORMS2); o.y = f2bf(m.y * NORMS2);
    o.z = f2bf(m.z * NORMS2); o.w = f2bf(m.w * NORMS2);
    *(short4*)&MB[i] = o;
}

// ---- transpose all 4 weights in one dispatch (z selects) ----
static __global__ __launch_bounds__(256) void wtrans4_kernel(
        const float* __restrict__ Wq, const float* __restrict__ Wk,
        const float* __restrict__ Wv, const float* __restrict__ Wo,
        short* __restrict__ QKh, short* __restrict__ QKl,
        short* __restrict__ VT, short* __restrict__ OT) {
    __shared__ float tile[32][33];
    const int z = blockIdx.z;
    const float* W = (z == 0) ? Wq : (z == 1) ? Wk : (z == 2) ? Wv : Wo;
    short* Th = (z <= 1) ? QKh : (z == 2) ? VT : OT;
    const int rowoff = (z == 1) ? 2048 : 0;
    const bool split = (z <= 1);
    int tx = threadIdx.x & 31, ty = threadIdx.x >> 5;
    int k0 = blockIdx.y * 32, n0 = blockIdx.x * 32;
    #pragma unroll
    for (int i = 0; i < 4; ++i)
        tile[ty + i * 8][tx] = W[(size_t)(k0 + ty + i * 8) * En + n0 + tx];
    __syncthreads();
    #pragma unroll
    for (int i = 0; i < 4; ++i) {
        float v = tile[tx][ty + i * 8];
        size_t idx = (size_t)(rowoff + n0 + ty + i * 8) * En + k0 + tx;
        short hv = f2bf(v);
        Th[idx] = hv;
        if (split) QKl[idx] = f2bf(v - bf2f(hv));
    }
}

// ---- MFMA GEMM: C[M][N] = A[M][K] * BT[N][K]^T, 128x128 tile, BK=32 ----
// NPROD=3: split products (hi*hi + hi*lo + lo*hi)
// OUTMODE=0: fp32 row-major -> Cf
// OUTMODE=1: bf16 V^T [(b,h,d)][s] via LDS transpose (coalesced) -> Cbt
// OUTMODE=3: packed (hi<<16|lo) int32 row-major, cols<2048 -> Qpk else Kpk
template<int NPROD, int OUTMODE>
static __global__ __launch_bounds__(256) void gemm_kernel(
        const short* __restrict__ Ahi, const short* __restrict__ Alo,
        const short* __restrict__ Bhi, const short* __restrict__ Blo,
        float* __restrict__ Cf, short* __restrict__ Cbt,
        int* __restrict__ Qpk, int* __restrict__ Kpk) {
    __shared__ short As_hi[128 * 32];
    __shared__ short Bs_hi[128 * 32];
    __shared__ short As_lo[NPROD == 3 ? 128 * 32 : 8];
    __shared__ short Bs_lo[NPROD == 3 ? 128 * 32 : 8];
    __shared__ short Ts[OUTMODE == 1 ? 128 * 136 : 8];

    const int tid = threadIdx.x;
    const int w = tid >> 6, l = tid & 63;
    const int quad = l >> 4, l15 = l & 15;
    const int wr = (w >> 1) * 64, wc = (w & 1) * 64;
    const int row0 = blockIdx.y * 128, col0 = blockIdx.x * 128;

    const int off0 = tid * 16;
    const int r_a = off0 >> 6;
    const int kb = (off0 & 63) >> 1;

    f32x4 acc[4][4];
    #pragma unroll
    for (int i = 0; i < 4; ++i)
        #pragma unroll
        for (int j = 0; j < 4; ++j) acc[i][j] = f32x4{0.f, 0.f, 0.f, 0.f};

    for (int k0 = 0; k0 < En; k0 += 32) {
        const short* ap = Ahi + (size_t)(row0 + r_a) * En + k0 + kb;
        const short* bp = Bhi + (size_t)(col0 + r_a) * En + k0 + kb;
        gl_lds16(ap,           &As_hi[off0 / 2]);
        gl_lds16(ap + 64 * En, &As_hi[(off0 + 4096) / 2]);
        gl_lds16(bp,           &Bs_hi[off0 / 2]);
        gl_lds16(bp + 64 * En, &Bs_hi[(off0 + 4096) / 2]);
        if constexpr (NPROD == 3) {
            const short* ap2 = Alo + (size_t)(row0 + r_a) * En + k0 + kb;
            const short* bp2 = Blo + (size_t)(col0 + r_a) * En + k0 + kb;
            gl_lds16(ap2,           &As_lo[off0 / 2]);
            gl_lds16(ap2 + 64 * En, &As_lo[(off0 + 4096) / 2]);
            gl_lds16(bp2,           &Bs_lo[off0 / 2]);
            gl_lds16(bp2 + 64 * En, &Bs_lo[(off0 + 4096) / 2]);
        }
        __syncthreads();

        short8 bhf[4], blf[4];
        #pragma unroll
        for (int ni = 0; ni < 4; ++ni) {
            bhf[ni] = *(const short8*)&Bs_hi[(wc + ni * 16 + l15) * 32 + quad * 8];
            if constexpr (NPROD == 3)
                blf[ni] = *(const short8*)&Bs_lo[(wc + ni * 16 + l15) * 32 + quad * 8];
        }
        #pragma unroll
        for (int mi = 0; mi < 4; ++mi) {
            short8 ahf = *(const short8*)&As_hi[(wr + mi * 16 + l15) * 32 + quad * 8];
            short8 alf;
            if constexpr (NPROD == 3)
                alf = *(const short8*)&As_lo[(wr + mi * 16 + l15) * 32 + quad * 8];
            #pragma unroll
            for (int ni = 0; ni < 4; ++ni) {
                acc[mi][ni] = __builtin_amdgcn_mfma_f32_16x16x32_bf16(ahf, bhf[ni], acc[mi][ni], 0, 0, 0);
                if constexpr (NPROD == 3) {
                    acc[mi][ni] = __builtin_amdgcn_mfma_f32_16x16x32_bf16(ahf, blf[ni], acc[mi][ni], 0, 0, 0);
                    acc[mi][ni] = __builtin_amdgcn_mfma_f32_16x16x32_bf16(alf, bhf[ni], acc[mi][ni], 0, 0, 0);
                }
            }
        }
        __syncthreads();
    }

    if constexpr (OUTMODE == 0) {
        #pragma unroll
        for (int mi = 0; mi < 4; ++mi)
            #pragma unroll
            for (int ni = 0; ni < 4; ++ni) {
                int r = row0 + wr + mi * 16 + quad * 4;
                int c = col0 + wc + ni * 16 + l15;
                #pragma unroll
                for (int reg = 0; reg < 4; ++reg)
                    Cf[(size_t)(r + reg) * En + c] = acc[mi][ni][reg];
            }
    } else if constexpr (OUTMODE == 1) {
        // LDS transpose -> coalesced V^T stores
        #pragma unroll
        for (int mi = 0; mi < 4; ++mi)
            #pragma unroll
            for (int ni = 0; ni < 4; ++ni) {
                int dl = wc + ni * 16 + l15;            // local col (d)
                int sl = wr + mi * 16 + quad * 4;       // local row (s)
                #pragma unroll
                for (int reg = 0; reg < 4; ++reg)
                    Ts[dl * 136 + sl + reg] = f2bf(acc[mi][ni][reg]);
            }
        __syncthreads();
        int dl = tid >> 1, s0 = (tid & 1) * 64;
        int b = row0 >> 11, h = col0 >> 7;
        size_t gbase = ((size_t)(b * Hn + h) * HDn + dl) * Sn + (row0 & (Sn - 1)) + s0;
        #pragma unroll
        for (int k = 0; k < 8; ++k) {
            short8 vv = *(const short8*)&Ts[dl * 136 + s0 + k * 8];
            *(short8*)&Cbt[gbase + k * 8] = vv;
        }
    } else {
        int* dst = (col0 >= 2048) ? Kpk : Qpk;
        const int cb = col0 & 2047;
        #pragma unroll
        for (int mi = 0; mi < 4; ++mi)
            #pragma unroll
            for (int ni = 0; ni < 4; ++ni) {
                int r = row0 + wr + mi * 16 + quad * 4;
                int c = cb + wc + ni * 16 + l15;
                #pragma unroll
                for (int reg = 0; reg < 4; ++reg) {
                    float v = acc[mi][ni][reg];
                    short hh = f2bf(v);
                    short ll = f2bf(v - bf2f(hh));
                    dst[(size_t)(r + reg) * 2048 + c] =
                        ((int)(unsigned short)hh << 16) | (unsigned short)ll;
                }
            }
    }
}

// ---- RoPE on packed (hi<<16|lo) int32 -> split bf16 planes ----
static __global__ void rope_pk_kernel(const int* __restrict__ Pre,
        short* __restrict__ Yh, short* __restrict__ Yl,
        const float* __restrict__ sinT, const float* __restrict__ cosT) {
    int p = blockIdx.x * 256 + threadIdx.x;       // < 2^21 ; 4 elements/thread
    int u = p & 511;
    int t = (p >> 9) & (Sn - 1);
    int b = p >> 20;
    int tsrc; float sgn;
    if (t < Sn / 2) { tsrc = 2 * t + 1; sgn = -1.f; }
    else            { tsrc = 2 * (t - Sn / 2); sgn = 1.f; }
    int f0 = (2 * u) & 63, f1 = (2 * u + 1) & 63;
    float sv0 = sinT[(t << 6) + f0], cv0 = cosT[(t << 6) + f0];
    float sv1 = sinT[(t << 6) + f1], cv1 = cosT[(t << 6) + f1];
    size_t rt = ((size_t)(b * Sn + t)) * 512 + u;     // int4 units
    size_t rs = ((size_t)(b * Sn + tsrc)) * 512 + u;
    int4 xt = ((const int4*)Pre)[rt];
    int4 xs = ((const int4*)Pre)[rs];
    auto up = [](int v) -> float {
        return bf2f((short)(v >> 16)) + bf2f((short)(v & 0xffff));
    };
    float x0 = up(xt.x), x1 = up(xt.y), x2 = up(xt.z), x3 = up(xt.w);
    float s0 = up(xs.x), s1 = up(xs.y), s2 = up(xs.z), s3 = up(xs.w);
    float y0 = x0 * cv0 + sgn * s0 * sv0;
    float y1 = x1 * cv0 + sgn * s1 * sv0;
    float y2 = x2 * cv1 + sgn * s2 * sv1;
    float y3 = x3 * cv1 + sgn * s3 * sv1;
    short4 hi, lo;
    hi.x = f2bf(y0); lo.x = f2bf(y0 - bf2f(hi.x));
    hi.y = f2bf(y1); lo.y = f2bf(y1 - bf2f(hi.y));
    hi.z = f2bf(y2); lo.z = f2bf(y2 - bf2f(hi.z));
    hi.w = f2bf(y3); lo.w = f2bf(y3 - bf2f(hi.w));
    size_t o = ((size_t)(b * Sn + t)) * En + 4 * u;
    *(short4*)&Yh[o] = hi;
    *(short4*)&Yl[o] = lo;
}

// ---- MFMA flash attention v8 ----
// 256 threads (4 waves), 128 q-rows/block (32 rows/wave in 2 row-halves),
// 64-key tiles; bf16 pre-scaled mask; same LDS image & size as v5 (69632 B,
// 2 blocks/CU). Each K/V LDS fragment read now feeds 2 MFMAs (rh=0,1) ->
// LDS read traffic per CU halves; numerics identical to v5.
// LDS (shorts): [0,8192)=K-hi  [8192,16384)=K-lo  [16384,24576)=V  [24576,34816)=P
// Q staging (prologue only): hi [0,16384) lo [16384,32768) shorts.
static __global__ __launch_bounds__(256, 2) void flash8_kernel(
        const short* __restrict__ Qhi, const short* __restrict__ Qlo,
        const short* __restrict__ Khi, const short* __restrict__ Klo,
        const short* __restrict__ Vt, const short* __restrict__ maskB,
        short* __restrict__ AO) {
    __shared__ short lds0[34816];

    const int tid = threadIdx.x;
    const int w = tid >> 6, l = tid & 63;
    const int quad = l >> 4, l15 = l & 15;
    const int n = blockIdx.x;
    const int bh = (n & 7) * 4 + ((n >> 3) & 3);   // heads grouped per XCD
    const int qt = n >> 5;                          // 32 consecutive blocks share mask rows
    const int b = bh >> 4, h = bh & 15;
    const int r0 = qt * 128;
    const size_t qkbase = (size_t)b * Sn * En + (size_t)h * HDn;
    const int psb = 24576 + w * 2560;               // 32 rows x 80 shorts per wave

    // ---- stage Q (128 rows, hi+lo) ----
    #pragma unroll
    for (int c = 0; c < 8; ++c) {
        int off = tid * 16 + c * 4096;              // bytes, [0,32768)
        int row = off >> 8;                         // 0..127
        int gp = (off >> 4) & 15;
        int gl = gp ^ (row & 7);
        size_t gidx = qkbase + (size_t)(r0 + row) * En + gl * 8;
        gl_lds16(Qhi + gidx, &lds0[off / 2]);
        gl_lds16(Qlo + gidx, &lds0[16384 + off / 2]);
    }
    __syncthreads();
    short8 qh[2][4], ql[2][4];
    #pragma unroll
    for (int rh = 0; rh < 2; ++rh) {
        int row = 32 * w + 16 * rh + l15;           // 0..127
        #pragma unroll
        for (int kc = 0; kc < 4; ++kc) {
            int gp = (kc * 4 + quad) ^ (row & 7);
            qh[rh][kc] = *(const short8*)&lds0[row * 128 + gp * 8];
            ql[rh][kc] = *(const short8*)&lds0[16384 + row * 128 + gp * 8];
        }
    }

    f32x4 O[2][8];
    #pragma unroll
    for (int rh = 0; rh < 2; ++rh)
        #pragma unroll
        for (int di = 0; di < 8; ++di) O[rh][di] = f32x4{0.f, 0.f, 0.f, 0.f};
    float m_prev[2][4], l_run[2][4];
    #pragma unroll
    for (int rh = 0; rh < 2; ++rh)
        #pragma unroll
        for (int reg = 0; reg < 4; ++reg) { m_prev[rh][reg] = -INFINITY; l_run[rh][reg] = 0.f; }
    const int qrow_base = r0 + 32 * w + quad * 4;   // + 16*rh + reg

    for (int j0 = 0; j0 < Sn; j0 += 64) {
        __syncthreads();                       // A: prev K/V readers done
        #pragma unroll
        for (int c = 0; c < 4; ++c) {          // stage K hi/lo (64 rows x 256 B each)
            int off = tid * 16 + c * 4096;     // [0,16384)
            int row = off >> 8;                // 0..63
            int gp = (off >> 4) & 15;
            int gl = gp ^ (row & 7);
            size_t gidx = qkbase + (size_t)(j0 + row) * En + gl * 8;
            gl_lds16(Khi + gidx, &lds0[off / 2]);
            gl_lds16(Klo + gidx, &lds0[8192 + off / 2]);
        }
        #pragma unroll
        for (int c = 0; c < 4; ++c) {          // stage V (128 d-rows x 128 B)
            int off = tid * 16 + c * 4096;     // [0,16384)
            int vrow = off >> 7;               // 0..127
            int vgp = (off >> 4) & 7;
            int vgl = vgp ^ (vrow & 7);
            size_t vidx = ((size_t)bh * HDn + vrow) * Sn + j0 + vgl * 8;
            gl_lds16(Vt + vidx, &lds0[16384 + off / 2]);
        }
        float mv[2][4][4];                     // bf16 mask prefetch (pre-scaled)
        #pragma unroll
        for (int rh = 0; rh < 2; ++rh)
            #pragma unroll
            for (int ni = 0; ni < 4; ++ni)
                #pragma unroll
                for (int reg = 0; reg < 4; ++reg)
                    mv[rh][ni][reg] = bf2f(maskB[(size_t)(qrow_base + 16 * rh + reg) * Sn + j0 + ni * 16 + l15]);
        __syncthreads();                       // B: K/V visible

        // ---- QK^T (3 split products, 2 row-halves share each K read) ----
        f32x4 p[2][4];
        #pragma unroll
        for (int rh = 0; rh < 2; ++rh)
            #pragma unroll
            for (int ni = 0; ni < 4; ++ni) p[rh][ni] = f32x4{0.f, 0.f, 0.f, 0.f};
        #pragma unroll
        for (int ni = 0; ni < 4; ++ni) {
            int col = ni * 16 + l15;
            #pragma unroll
            for (int kc = 0; kc < 4; ++kc) {
                int gp = (kc * 4 + quad) ^ (col & 7);
                short8 kh = *(const short8*)&lds0[col * 128 + gp * 8];
                short8 kl = *(const short8*)&lds0[8192 + col * 128 + gp * 8];
                #pragma unroll
                for (int rh = 0; rh < 2; ++rh) {
                    p[rh][ni] = __builtin_amdgcn_mfma_f32_16x16x32_bf16(qh[rh][kc], kh, p[rh][ni], 0, 0, 0);
                    p[rh][ni] = __builtin_amdgcn_mfma_f32_16x16x32_bf16(qh[rh][kc], kl, p[rh][ni], 0, 0, 0);
                    p[rh][ni] = __builtin_amdgcn_mfma_f32_16x16x32_bf16(ql[rh][kc], kh, p[rh][ni], 0, 0, 0);
                }
            }
        }

        // ---- softmax in base 2, DPP reductions (v5 math, per row-half) ----
        #pragma unroll
        for (int rh = 0; rh < 2; ++rh) {
            float rm[4] = {-INFINITY, -INFINITY, -INFINITY, -INFINITY};
            #pragma unroll
            for (int ni = 0; ni < 4; ++ni)
                #pragma unroll
                for (int reg = 0; reg < 4; ++reg) {
                    float v = fmaf(p[rh][ni][reg], NORMS2, mv[rh][ni][reg]);
                    p[rh][ni][reg] = v;
                    rm[reg] = fmaxf(rm[reg], v);
                }
            #pragma unroll
            for (int reg = 0; reg < 4; ++reg) rm[reg] = redmax16(rm[reg]);
            float al[4], mn[4], rs[4];
            #pragma unroll
            for (int reg = 0; reg < 4; ++reg) {
                mn[reg] = fmaxf(m_prev[rh][reg], rm[reg]);
                al[reg] = EXP2(m_prev[rh][reg] - mn[reg]);
                rs[reg] = 0.f;
            }
            #pragma unroll
            for (int ni = 0; ni < 4; ++ni)
                #pragma unroll
                for (int reg = 0; reg < 4; ++reg) {
                    float pe = EXP2(p[rh][ni][reg] - mn[reg]);
                    rs[reg] += pe;
                    lds0[psb + (rh * 16 + quad * 4 + reg) * 80 + ((ni ^ quad) << 4) + l15] = f2bf(pe);
                }
            #pragma unroll
            for (int reg = 0; reg < 4; ++reg) rs[reg] = redsum16(rs[reg]);
            #pragma unroll
            for (int reg = 0; reg < 4; ++reg) {
                l_run[rh][reg] = l_run[rh][reg] * al[reg] + rs[reg];
                m_prev[rh][reg] = mn[reg];
            }
            #pragma unroll
            for (int di = 0; di < 8; ++di)
                #pragma unroll
                for (int reg = 0; reg < 4; ++reg)
                    O[rh][di][reg] *= al[reg];
        }

        short8 pa[2][2];
        #pragma unroll
        for (int rh = 0; rh < 2; ++rh)
            #pragma unroll
            for (int kc2 = 0; kc2 < 2; ++kc2) {
                int g = kc2 * 2 + (quad >> 1);
                int gs = g ^ (l15 >> 2);
                pa[rh][kc2] = *(const short8*)&lds0[psb + (rh * 16 + l15) * 80 + (gs << 4) + (quad & 1) * 8];
            }

        // ---- PV (2 row-halves share each V read) ----
        #pragma unroll
        for (int di = 0; di < 8; ++di) {
            int d = di * 16 + l15;
            #pragma unroll
            for (int kc2 = 0; kc2 < 2; ++kc2) {
                int gp = (kc2 * 4 + quad) ^ (d & 7);
                short8 vb = *(const short8*)&lds0[16384 + d * 64 + gp * 8];
                #pragma unroll
                for (int rh = 0; rh < 2; ++rh)
                    O[rh][di] = __builtin_amdgcn_mfma_f32_16x16x32_bf16(pa[rh][kc2], vb, O[rh][di], 0, 0, 0);
            }
        }
    }

    #pragma unroll
    for (int rh = 0; rh < 2; ++rh) {
        float inv[4];
        #pragma unroll
        for (int reg = 0; reg < 4; ++reg) inv[reg] = 1.0f / l_run[rh][reg];
        #pragma unroll
        for (int di = 0; di < 8; ++di)
            #pragma unroll
            for (int reg = 0; reg < 4; ++reg) {
                size_t idx = ((size_t)b * Sn + qrow_base + 16 * rh + reg) * En + h * HDn + di * 16 + l15;
                AO[idx] = f2bf(O[rh][di][reg] * inv[reg]);
            }
    }
}

extern "C" void kernel_launch(void* const* d_in, const int* in_sizes, int n_in,
                              void* d_out, int out_size, void* d_ws, size_t ws_size,
                              hipStream_t stream) {
    const float* inputs = (const float*)d_in[0];
    const float* mask   = (const float*)d_in[1];
    const float* wq     = (const float*)d_in[2];
    const float* wk     = (const float*)d_in[3];
    const float* wv     = (const float*)d_in[4];
    const float* wo     = (const float*)d_in[5];
    float* out = (float*)d_out;
    (void)in_sizes; (void)n_in; (void)out_size; (void)ws_size;

    char* W8 = (char*)d_ws;
    float* sinT  = (float*)(W8 + 0);
    float* cosT  = (float*)(W8 + 524288);
    short* Xhi   = (short*)(W8 + 1048576);
    short* Xlo   = (short*)(W8 + 17825792);
    short* maskB = (short*)(W8 + 34603008);
    short* WqkTh = (short*)(W8 + 42991616);
    short* WqkTl = (short*)(W8 + 59768832);
    short* WvT   = (short*)(W8 + 76546048);
    short* WoT   = (short*)(W8 + 84934656);
    int*   Qpk   = (int*)(W8 + 93323264);
    int*   Kpk   = (int*)(W8 + 126877696);
    // aliases (lifetimes disjoint; ordering enforced by dispatch sequence):
    short* Qhi = WqkTh;                        // rope-Q out over W-qk (dead after QK-GEMM)
    short* Qlo = WqkTl;
    short* Khi = (short*)(W8 + 93323264);      // rope-K out over Qpk (dead after rope-Q)
    short* Klo = (short*)(W8 + 110100480);
    short* Vt  = (short*)(W8 + 126877696);     // V^T over Kpk (dead after rope-K)
    short* AO  = Xhi;                          // flash out over X-hi (dead after V-GEMM)

    rope_table_kernel<<<512, 256, 0, stream>>>(sinT, cosT);
    split_x_kernel<<<8192, 256, 0, stream>>>(inputs, Xhi, Xlo);
    maskconv_kernel<<<4096, 256, 0, stream>>>(mask, maskB);
    wtrans4_kernel<<<dim3(64, 64, 4), 256, 0, stream>>>(wq, wk, wv, wo,
                                                        WqkTh, WqkTl, WvT, WoT);

    gemm_kernel<3, 3><<<dim3(32, 32), 256, 0, stream>>>(
        Xhi, Xlo, WqkTh, WqkTl, nullptr, nullptr, Qpk, Kpk);
    rope_pk_kernel<<<8192, 256, 0, stream>>>(Qpk, Qhi, Qlo, sinT, cosT);
    rope_pk_kernel<<<8192, 256, 0, stream>>>(Kpk, Khi, Klo, sinT, cosT);
    gemm_kernel<1, 1><<<dim3(16, 32), 256, 0, stream>>>(
        Xhi, nullptr, WvT, nullptr, nullptr, Vt, nullptr, nullptr);

    flash8_kernel<<<512, 256, 0, stream>>>(Qhi, Qlo, Khi, Klo, Vt, maskB, AO);

    gemm_kernel<1, 0><<<dim3(16, 32), 256, 0, stream>>>(
        AO, nullptr, WoT, nullptr, out, nullptr, nullptr, nullptr);
}

// Round 4
// 678.963 us; speedup vs baseline: 1.1053x; 1.1053x over previous
//
#include <hip/hip_runtime.h>
#include <hip/hip_bf16.h>
#include <cmath>

#define Bn 2
#define Sn 2048
#define En 2048
#define Hn 16
#define HDn 128
#define Mn (Bn*Sn)
#define NORMS2 92.33248261689366f   /* 64 * log2(e) : softmax done in base 2 */

typedef __attribute__((ext_vector_type(8))) short short8;
typedef __attribute__((ext_vector_type(4))) float f32x4;

__device__ __forceinline__ short f2bf(float x) {
    __hip_bfloat16 h = __float2bfloat16(x);
    return *reinterpret_cast<short*>(&h);
}
__device__ __forceinline__ float bf2f(short s) {
    __hip_bfloat16 h = *reinterpret_cast<__hip_bfloat16*>(&s);
    return __bfloat162float(h);
}
__device__ __forceinline__ void gl_lds16(const void* g, void* l) {
    __builtin_amdgcn_global_load_lds(
        (const __attribute__((address_space(1))) unsigned int*)g,
        (__attribute__((address_space(3))) unsigned int*)l, 16, 0, 0);
}

#if __has_builtin(__builtin_amdgcn_exp2f)
#define EXP2(x) __builtin_amdgcn_exp2f(x)
#else
#define EXP2(x) exp2f(x)
#endif

template<int CTRL>
__device__ __forceinline__ float dppf(float x) {
    int r = __builtin_amdgcn_update_dpp(0, __builtin_bit_cast(int, x), CTRL, 0xf, 0xf, true);
    return __builtin_bit_cast(float, r);
}
__device__ __forceinline__ float redmax16(float x) {
    x = fmaxf(x, dppf<0xB1>(x));   // quad_perm xor1
    x = fmaxf(x, dppf<0x4E>(x));   // quad_perm xor2
    x = fmaxf(x, dppf<0x141>(x));  // row_half_mirror xor7
    x = fmaxf(x, dppf<0x140>(x));  // row_mirror xor15
    return x;
}
__device__ __forceinline__ float redsum16(float x) {
    x += dppf<0xB1>(x);
    x += dppf<0x4E>(x);
    x += dppf<0x141>(x);
    x += dppf<0x140>(x);
    return x;
}

// ---- sin/cos tables in fp64 ----
static __global__ void rope_table_kernel(float* __restrict__ sinT, float* __restrict__ cosT) {
    int i = blockIdx.x * 256 + threadIdx.x;
    int t = i >> 6, f = i & 63;
    double inv = pow(10000.0, -(double)(2 * f) / (double)HDn);
    double ang = (double)t * inv;
    sinT[i] = (float)sin(ang);
    cosT[i] = (float)cos(ang);
}

// ---- split fp32 -> bf16 hi/lo ----
static __global__ void split_x_kernel(const float* __restrict__ X,
                                      short* __restrict__ Xhi, short* __restrict__ Xlo) {
    int i = (blockIdx.x * 256 + threadIdx.x) * 4;
    float4 x = *(const float4*)&X[i];
    short4 hi, lo;
    hi.x = f2bf(x.x); lo.x = f2bf(x.x - bf2f(hi.x));
    hi.y = f2bf(x.y); lo.y = f2bf(x.y - bf2f(hi.y));
    hi.z = f2bf(x.z); lo.z = f2bf(x.z - bf2f(hi.z));
    hi.w = f2bf(x.w); lo.w = f2bf(x.w - bf2f(hi.w));
    *(short4*)&Xhi[i] = hi;
    *(short4*)&Xlo[i] = lo;
}

// ---- mask fp32 -> bf16, pre-scaled by NORMS2 (exact for zero mask) ----
static __global__ void maskconv_kernel(const float* __restrict__ M, short* __restrict__ MB) {
    int i = (blockIdx.x * 256 + threadIdx.x) * 4;
    float4 m = *(const float4*)&M[i];
    short4 o;
    o.x = f2bf(m.x * NORMS2); o.y = f2bf(m.y * NORMS2);
    o.z = f2bf(m.z * NORMS2); o.w = f2bf(m.w * NORMS2);
    *(short4*)&MB[i] = o;
}

// ---- transpose all 4 weights in one dispatch (z selects) ----
static __global__ __launch_bounds__(256) void wtrans4_kernel(
        const float* __restrict__ Wq, const float* __restrict__ Wk,
        const float* __restrict__ Wv, const float* __restrict__ Wo,
        short* __restrict__ QKh, short* __restrict__ QKl,
        short* __restrict__ VT, short* __restrict__ OT) {
    __shared__ float tile[32][33];
    const int z = blockIdx.z;
    const float* W = (z == 0) ? Wq : (z == 1) ? Wk : (z == 2) ? Wv : Wo;
    short* Th = (z <= 1) ? QKh : (z == 2) ? VT : OT;
    const int rowoff = (z == 1) ? 2048 : 0;
    const bool split = (z <= 1);
    int tx = threadIdx.x & 31, ty = threadIdx.x >> 5;
    int k0 = blockIdx.y * 32, n0 = blockIdx.x * 32;
    #pragma unroll
    for (int i = 0; i < 4; ++i)
        tile[ty + i * 8][tx] = W[(size_t)(k0 + ty + i * 8) * En + n0 + tx];
    __syncthreads();
    #pragma unroll
    for (int i = 0; i < 4; ++i) {
        float v = tile[tx][ty + i * 8];
        size_t idx = (size_t)(rowoff + n0 + ty + i * 8) * En + k0 + tx;
        short hv = f2bf(v);
        Th[idx] = hv;
        if (split) QKl[idx] = f2bf(v - bf2f(hv));
    }
}

// ---- MFMA GEMM: C[M][N] = A[M][K] * BT[N][K]^T, 128x128 tile, BK=32 ----
// NPROD=3: split products (hi*hi + hi*lo + lo*hi)
// OUTMODE=0: fp32 row-major -> Cf
// OUTMODE=1: bf16 V^T [(b,h,d)][s] via LDS transpose (coalesced) -> Cbt
// OUTMODE=3: packed (hi<<16|lo) int32 row-major, cols<2048 -> Qpk else Kpk
template<int NPROD, int OUTMODE>
static __global__ __launch_bounds__(256) void gemm_kernel(
        const short* __restrict__ Ahi, const short* __restrict__ Alo,
        const short* __restrict__ Bhi, const short* __restrict__ Blo,
        float* __restrict__ Cf, short* __restrict__ Cbt,
        int* __restrict__ Qpk, int* __restrict__ Kpk) {
    __shared__ short As_hi[128 * 32];
    __shared__ short Bs_hi[128 * 32];
    __shared__ short As_lo[NPROD == 3 ? 128 * 32 : 8];
    __shared__ short Bs_lo[NPROD == 3 ? 128 * 32 : 8];
    __shared__ short Ts[OUTMODE == 1 ? 128 * 136 : 8];

    const int tid = threadIdx.x;
    const int w = tid >> 6, l = tid & 63;
    const int quad = l >> 4, l15 = l & 15;
    const int wr = (w >> 1) * 64, wc = (w & 1) * 64;
    const int row0 = blockIdx.y * 128, col0 = blockIdx.x * 128;

    const int off0 = tid * 16;
    const int r_a = off0 >> 6;
    const int kb = (off0 & 63) >> 1;

    f32x4 acc[4][4];
    #pragma unroll
    for (int i = 0; i < 4; ++i)
        #pragma unroll
        for (int j = 0; j < 4; ++j) acc[i][j] = f32x4{0.f, 0.f, 0.f, 0.f};

    for (int k0 = 0; k0 < En; k0 += 32) {
        const short* ap = Ahi + (size_t)(row0 + r_a) * En + k0 + kb;
        const short* bp = Bhi + (size_t)(col0 + r_a) * En + k0 + kb;
        gl_lds16(ap,           &As_hi[off0 / 2]);
        gl_lds16(ap + 64 * En, &As_hi[(off0 + 4096) / 2]);
        gl_lds16(bp,           &Bs_hi[off0 / 2]);
        gl_lds16(bp + 64 * En, &Bs_hi[(off0 + 4096) / 2]);
        if constexpr (NPROD == 3) {
            const short* ap2 = Alo + (size_t)(row0 + r_a) * En + k0 + kb;
            const short* bp2 = Blo + (size_t)(col0 + r_a) * En + k0 + kb;
            gl_lds16(ap2,           &As_lo[off0 / 2]);
            gl_lds16(ap2 + 64 * En, &As_lo[(off0 + 4096) / 2]);
            gl_lds16(bp2,           &Bs_lo[off0 / 2]);
            gl_lds16(bp2 + 64 * En, &Bs_lo[(off0 + 4096) / 2]);
        }
        __syncthreads();

        short8 bhf[4], blf[4];
        #pragma unroll
        for (int ni = 0; ni < 4; ++ni) {
            bhf[ni] = *(const short8*)&Bs_hi[(wc + ni * 16 + l15) * 32 + quad * 8];
            if constexpr (NPROD == 3)
                blf[ni] = *(const short8*)&Bs_lo[(wc + ni * 16 + l15) * 32 + quad * 8];
        }
        #pragma unroll
        for (int mi = 0; mi < 4; ++mi) {
            short8 ahf = *(const short8*)&As_hi[(wr + mi * 16 + l15) * 32 + quad * 8];
            short8 alf;
            if constexpr (NPROD == 3)
                alf = *(const short8*)&As_lo[(wr + mi * 16 + l15) * 32 + quad * 8];
            #pragma unroll
            for (int ni = 0; ni < 4; ++ni) {
                acc[mi][ni] = __builtin_amdgcn_mfma_f32_16x16x32_bf16(ahf, bhf[ni], acc[mi][ni], 0, 0, 0);
                if constexpr (NPROD == 3) {
                    acc[mi][ni] = __builtin_amdgcn_mfma_f32_16x16x32_bf16(ahf, blf[ni], acc[mi][ni], 0, 0, 0);
                    acc[mi][ni] = __builtin_amdgcn_mfma_f32_16x16x32_bf16(alf, bhf[ni], acc[mi][ni], 0, 0, 0);
                }
            }
        }
        __syncthreads();
    }

    if constexpr (OUTMODE == 0) {
        #pragma unroll
        for (int mi = 0; mi < 4; ++mi)
            #pragma unroll
            for (int ni = 0; ni < 4; ++ni) {
                int r = row0 + wr + mi * 16 + quad * 4;
                int c = col0 + wc + ni * 16 + l15;
                #pragma unroll
                for (int reg = 0; reg < 4; ++reg)
                    Cf[(size_t)(r + reg) * En + c] = acc[mi][ni][reg];
            }
    } else if constexpr (OUTMODE == 1) {
        // LDS transpose -> coalesced V^T stores
        #pragma unroll
        for (int mi = 0; mi < 4; ++mi)
            #pragma unroll
            for (int ni = 0; ni < 4; ++ni) {
                int dl = wc + ni * 16 + l15;            // local col (d)
                int sl = wr + mi * 16 + quad * 4;       // local row (s)
                #pragma unroll
                for (int reg = 0; reg < 4; ++reg)
                    Ts[dl * 136 + sl + reg] = f2bf(acc[mi][ni][reg]);
            }
        __syncthreads();
        int dl = tid >> 1, s0 = (tid & 1) * 64;
        int b = row0 >> 11, h = col0 >> 7;
        size_t gbase = ((size_t)(b * Hn + h) * HDn + dl) * Sn + (row0 & (Sn - 1)) + s0;
        #pragma unroll
        for (int k = 0; k < 8; ++k) {
            short8 vv = *(const short8*)&Ts[dl * 136 + s0 + k * 8];
            *(short8*)&Cbt[gbase + k * 8] = vv;
        }
    } else {
        int* dst = (col0 >= 2048) ? Kpk : Qpk;
        const int cb = col0 & 2047;
        #pragma unroll
        for (int mi = 0; mi < 4; ++mi)
            #pragma unroll
            for (int ni = 0; ni < 4; ++ni) {
                int r = row0 + wr + mi * 16 + quad * 4;
                int c = cb + wc + ni * 16 + l15;
                #pragma unroll
                for (int reg = 0; reg < 4; ++reg) {
                    float v = acc[mi][ni][reg];
                    short hh = f2bf(v);
                    short ll = f2bf(v - bf2f(hh));
                    dst[(size_t)(r + reg) * 2048 + c] =
                        ((int)(unsigned short)hh << 16) | (unsigned short)ll;
                }
            }
    }
}

// ---- RoPE on packed (hi<<16|lo) int32 -> split bf16 planes ----
static __global__ void rope_pk_kernel(const int* __restrict__ Pre,
        short* __restrict__ Yh, short* __restrict__ Yl,
        const float* __restrict__ sinT, const float* __restrict__ cosT) {
    int p = blockIdx.x * 256 + threadIdx.x;       // < 2^21 ; 4 elements/thread
    int u = p & 511;
    int t = (p >> 9) & (Sn - 1);
    int b = p >> 20;
    int tsrc; float sgn;
    if (t < Sn / 2) { tsrc = 2 * t + 1; sgn = -1.f; }
    else            { tsrc = 2 * (t - Sn / 2); sgn = 1.f; }
    int f0 = (2 * u) & 63, f1 = (2 * u + 1) & 63;
    float sv0 = sinT[(t << 6) + f0], cv0 = cosT[(t << 6) + f0];
    float sv1 = sinT[(t << 6) + f1], cv1 = cosT[(t << 6) + f1];
    size_t rt = ((size_t)(b * Sn + t)) * 512 + u;     // int4 units
    size_t rs = ((size_t)(b * Sn + tsrc)) * 512 + u;
    int4 xt = ((const int4*)Pre)[rt];
    int4 xs = ((const int4*)Pre)[rs];
    auto up = [](int v) -> float {
        return bf2f((short)(v >> 16)) + bf2f((short)(v & 0xffff));
    };
    float x0 = up(xt.x), x1 = up(xt.y), x2 = up(xt.z), x3 = up(xt.w);
    float s0 = up(xs.x), s1 = up(xs.y), s2 = up(xs.z), s3 = up(xs.w);
    float y0 = x0 * cv0 + sgn * s0 * sv0;
    float y1 = x1 * cv0 + sgn * s1 * sv0;
    float y2 = x2 * cv1 + sgn * s2 * sv1;
    float y3 = x3 * cv1 + sgn * s3 * sv1;
    short4 hi, lo;
    hi.x = f2bf(y0); lo.x = f2bf(y0 - bf2f(hi.x));
    hi.y = f2bf(y1); lo.y = f2bf(y1 - bf2f(hi.y));
    hi.z = f2bf(y2); lo.z = f2bf(y2 - bf2f(hi.z));
    hi.w = f2bf(y3); lo.w = f2bf(y3 - bf2f(hi.w));
    size_t o = ((size_t)(b * Sn + t)) * En + 4 * u;
    *(short4*)&Yh[o] = hi;
    *(short4*)&Yl[o] = lo;
}

// ---- MFMA flash attention v9 ----
// 512 threads (8 waves), 128 q-rows/block, 64-key tiles; flash5 per-tile
// compute (identical numerics) + K/V LDS DOUBLE-BUFFER with stage-early /
// drain-late: stage tile j+1 into buf^1 at top of iter, compute tile j from
// buf, ONE __syncthreads per tile at the END. The implicit vmcnt(0) drain at
// that barrier hits loads issued a full compute-phase earlier -> ~free.
// (flash5 drained immediately after issue -> exposed latency; flash8 showed
// the kernel is latency-bound, not LDS-throughput-bound.)
// LDS (shorts): buf0 [0,24576): K-hi/K-lo/V each 8192
//               buf1 [24576,49152): same layout
//               P    [49152,59392): 8 waves x 1280
// Q staged transiently in [0,32768) before buffers are first used.
// 118784 B -> 1 block/CU (8 waves).
static __global__ __launch_bounds__(512, 2) void flash9_kernel(
        const short* __restrict__ Qhi, const short* __restrict__ Qlo,
        const short* __restrict__ Khi, const short* __restrict__ Klo,
        const short* __restrict__ Vt, const short* __restrict__ maskB,
        short* __restrict__ AO) {
    __shared__ short lds0[59392];

    const int tid = threadIdx.x;
    const int w = tid >> 6, l = tid & 63;
    const int quad = l >> 4, l15 = l & 15;
    const int n = blockIdx.x;
    const int bh = (n & 7) * 4 + ((n >> 3) & 3);   // heads grouped per XCD
    const int qt = n >> 5;                          // 32 consecutive blocks share mask rows
    const int b = bh >> 4, h = bh & 15;
    const int r0 = qt * 128;
    const size_t qkbase = (size_t)b * Sn * En + (size_t)h * HDn;
    const int psb = 49152 + w * 1280;

    // ---- stage Q (transient, overlaps buffer region) ----
    #pragma unroll
    for (int c = 0; c < 4; ++c) {
        int off = tid * 16 + c * 8192;
        int row = off >> 8;
        int gp = (off >> 4) & 15;
        int gl = gp ^ (row & 7);
        size_t gidx = qkbase + (size_t)(r0 + row) * En + gl * 8;
        gl_lds16(Qhi + gidx, &lds0[off / 2]);
        gl_lds16(Qlo + gidx, &lds0[16384 + off / 2]);
    }
    __syncthreads();
    short8 qh[4], ql[4];
    {
        int row = 16 * w + l15;
        #pragma unroll
        for (int kc = 0; kc < 4; ++kc) {
            int gp = (kc * 4 + quad) ^ (row & 7);
            qh[kc] = *(const short8*)&lds0[row * 128 + gp * 8];
            ql[kc] = *(const short8*)&lds0[16384 + row * 128 + gp * 8];
        }
    }
    __syncthreads();   // all waves done reading Q before buffers are written

    // ---- staging helper: K hi/lo + V for key-tile jj into buffer at bbase ----
    auto STAGE = [&](int bbase, int jj) {
        #pragma unroll
        for (int c = 0; c < 2; ++c) {          // K hi/lo (64 rows x 256 B)
            int off = tid * 16 + c * 8192;     // [0,16384) bytes
            int row = off >> 8;                // 0..63
            int gp = (off >> 4) & 15;
            int gl = gp ^ (row & 7);
            size_t gidx = qkbase + (size_t)(jj + row) * En + gl * 8;
            gl_lds16(Khi + gidx, &lds0[bbase + off / 2]);
            gl_lds16(Klo + gidx, &lds0[bbase + 8192 + off / 2]);
        }
        #pragma unroll
        for (int c = 0; c < 2; ++c) {          // V (128 d-rows x 128 B)
            int off = tid * 16 + c * 8192;     // [0,16384) bytes
            int vrow = off >> 7;               // 0..127
            int vgp = (off >> 4) & 7;
            int vgl = vgp ^ (vrow & 7);
            size_t vidx = ((size_t)bh * HDn + vrow) * Sn + jj + vgl * 8;
            gl_lds16(Vt + vidx, &lds0[bbase + 16384 + off / 2]);
        }
    };

    STAGE(0, 0);          // tile 0 -> buf0
    __syncthreads();      // only prologue drain that exposes latency

    f32x4 O[8];
    #pragma unroll
    for (int di = 0; di < 8; ++di) O[di] = f32x4{0.f, 0.f, 0.f, 0.f};
    float m_prev[4] = {-INFINITY, -INFINITY, -INFINITY, -INFINITY};
    float l_run[4] = {0.f, 0.f, 0.f, 0.f};
    const int qrow_base = r0 + 16 * w + quad * 4;

    for (int j0 = 0; j0 < Sn; j0 += 64) {
        const int bb = ((j0 >> 6) & 1) * 24576;   // current buffer base
        const int nb = bb ^ 24576;                // next buffer base

        float mv[4][4];                        // bf16 mask prefetch (pre-scaled)
        #pragma unroll
        for (int ni = 0; ni < 4; ++ni)
            #pragma unroll
            for (int reg = 0; reg < 4; ++reg)
                mv[ni][reg] = bf2f(maskB[(size_t)(qrow_base + reg) * Sn + j0 + ni * 16 + l15]);

        if (j0 + 64 < Sn) STAGE(nb, j0 + 64);  // prefetch next tile (drained at end-of-iter barrier)

        // ---- QK^T (3 split products) from buf[bb] ----
        f32x4 p[4];
        #pragma unroll
        for (int ni = 0; ni < 4; ++ni) p[ni] = f32x4{0.f, 0.f, 0.f, 0.f};
        #pragma unroll
        for (int ni = 0; ni < 4; ++ni) {
            int col = ni * 16 + l15;
            #pragma unroll
            for (int kc = 0; kc < 4; ++kc) {
                int gp = (kc * 4 + quad) ^ (col & 7);
                short8 kh = *(const short8*)&lds0[bb + col * 128 + gp * 8];
                short8 kl = *(const short8*)&lds0[bb + 8192 + col * 128 + gp * 8];
                p[ni] = __builtin_amdgcn_mfma_f32_16x16x32_bf16(qh[kc], kh, p[ni], 0, 0, 0);
                p[ni] = __builtin_amdgcn_mfma_f32_16x16x32_bf16(qh[kc], kl, p[ni], 0, 0, 0);
                p[ni] = __builtin_amdgcn_mfma_f32_16x16x32_bf16(ql[kc], kh, p[ni], 0, 0, 0);
            }
        }

        // ---- softmax in base 2, DPP reductions (flash5 math, unchanged) ----
        float rm[4] = {-INFINITY, -INFINITY, -INFINITY, -INFINITY};
        #pragma unroll
        for (int ni = 0; ni < 4; ++ni)
            #pragma unroll
            for (int reg = 0; reg < 4; ++reg) {
                float v = fmaf(p[ni][reg], NORMS2, mv[ni][reg]);
                p[ni][reg] = v;
                rm[reg] = fmaxf(rm[reg], v);
            }
        #pragma unroll
        for (int reg = 0; reg < 4; ++reg) rm[reg] = redmax16(rm[reg]);
        float al[4], mn[4], rs[4];
        #pragma unroll
        for (int reg = 0; reg < 4; ++reg) {
            mn[reg] = fmaxf(m_prev[reg], rm[reg]);
            al[reg] = EXP2(m_prev[reg] - mn[reg]);
            rs[reg] = 0.f;
        }
        #pragma unroll
        for (int ni = 0; ni < 4; ++ni)
            #pragma unroll
            for (int reg = 0; reg < 4; ++reg) {
                float pe = EXP2(p[ni][reg] - mn[reg]);
                rs[reg] += pe;
                lds0[psb + (quad * 4 + reg) * 80 + ((ni ^ quad) << 4) + l15] = f2bf(pe);
            }
        #pragma unroll
        for (int reg = 0; reg < 4; ++reg) rs[reg] = redsum16(rs[reg]);
        #pragma unroll
        for (int reg = 0; reg < 4; ++reg) {
            l_run[reg] = l_run[reg] * al[reg] + rs[reg];
            m_prev[reg] = mn[reg];
        }
        #pragma unroll
        for (int di = 0; di < 8; ++di)
            #pragma unroll
            for (int reg = 0; reg < 4; ++reg)
                O[di][reg] *= al[reg];

        short8 pa[2];
        #pragma unroll
        for (int kc2 = 0; kc2 < 2; ++kc2) {
            int g = kc2 * 2 + (quad >> 1);
            int gs = g ^ (l15 >> 2);
            pa[kc2] = *(const short8*)&lds0[psb + l15 * 80 + (gs << 4) + (quad & 1) * 8];
        }

        // ---- PV from buf[bb] ----
        #pragma unroll
        for (int di = 0; di < 8; ++di) {
            int d = di * 16 + l15;
            #pragma unroll
            for (int kc2 = 0; kc2 < 2; ++kc2) {
                int gp = (kc2 * 4 + quad) ^ (d & 7);
                short8 vb = *(const short8*)&lds0[bb + 16384 + d * 64 + gp * 8];
                O[di] = __builtin_amdgcn_mfma_f32_16x16x32_bf16(pa[kc2], vb, O[di], 0, 0, 0);
            }
        }

        // ONE barrier per tile: prev-iter prefetch now visible to all waves,
        // and buf[bb] is free to be overwritten next iteration. The implicit
        // vmcnt(0) drain targets loads issued before the compute phase.
        __syncthreads();
    }

    float inv[4];
    #pragma unroll
    for (int reg = 0; reg < 4; ++reg) inv[reg] = 1.0f / l_run[reg];
    #pragma unroll
    for (int di = 0; di < 8; ++di)
        #pragma unroll
        for (int reg = 0; reg < 4; ++reg) {
            size_t idx = ((size_t)b * Sn + qrow_base + reg) * En + h * HDn + di * 16 + l15;
            AO[idx] = f2bf(O[di][reg] * inv[reg]);
        }
}

extern "C" void kernel_launch(void* const* d_in, const int* in_sizes, int n_in,
                              void* d_out, int out_size, void* d_ws, size_t ws_size,
                              hipStream_t stream) {
    const float* inputs = (const float*)d_in[0];
    const float* mask   = (const float*)d_in[1];
    const float* wq     = (const float*)d_in[2];
    const float* wk     = (const float*)d_in[3];
    const float* wv     = (const float*)d_in[4];
    const float* wo     = (const float*)d_in[5];
    float* out = (float*)d_out;
    (void)in_sizes; (void)n_in; (void)out_size; (void)ws_size;

    char* W8 = (char*)d_ws;
    float* sinT  = (float*)(W8 + 0);
    float* cosT  = (float*)(W8 + 524288);
    short* Xhi   = (short*)(W8 + 1048576);
    short* Xlo   = (short*)(W8 + 17825792);
    short* maskB = (short*)(W8 + 34603008);
    short* WqkTh = (short*)(W8 + 42991616);
    short* WqkTl = (short*)(W8 + 59768832);
    short* WvT   = (short*)(W8 + 76546048);
    short* WoT   = (short*)(W8 + 84934656);
    int*   Qpk   = (int*)(W8 + 93323264);
    int*   Kpk   = (int*)(W8 + 126877696);
    // aliases (lifetimes disjoint; ordering enforced by dispatch sequence):
    short* Qhi = WqkTh;                        // rope-Q out over W-qk (dead after QK-GEMM)
    short* Qlo = WqkTl;
    short* Khi = (short*)(W8 + 93323264);      // rope-K out over Qpk (dead after rope-Q)
    short* Klo = (short*)(W8 + 110100480);
    short* Vt  = (short*)(W8 + 126877696);     // V^T over Kpk (dead after rope-K)
    short* AO  = Xhi;                          // flash out over X-hi (dead after V-GEMM)

    rope_table_kernel<<<512, 256, 0, stream>>>(sinT, cosT);
    split_x_kernel<<<8192, 256, 0, stream>>>(inputs, Xhi, Xlo);
    maskconv_kernel<<<4096, 256, 0, stream>>>(mask, maskB);
    wtrans4_kernel<<<dim3(64, 64, 4), 256, 0, stream>>>(wq, wk, wv, wo,
                                                        WqkTh, WqkTl, WvT, WoT);

    gemm_kernel<3, 3><<<dim3(32, 32), 256, 0, stream>>>(
        Xhi, Xlo, WqkTh, WqkTl, nullptr, nullptr, Qpk, Kpk);
    rope_pk_kernel<<<8192, 256, 0, stream>>>(Qpk, Qhi, Qlo, sinT, cosT);
    rope_pk_kernel<<<8192, 256, 0, stream>>>(Kpk, Khi, Klo, sinT, cosT);
    gemm_kernel<1, 1><<<dim3(16, 32), 256, 0, stream>>>(
        Xhi, nullptr, WvT, nullptr, nullptr, Vt, nullptr, nullptr);

    flash9_kernel<<<512, 512, 0, stream>>>(Qhi, Qlo, Khi, Klo, Vt, maskB, AO);

    gemm_kernel<1, 0><<<dim3(16, 32), 256, 0, stream>>>(
        AO, nullptr, WoT, nullptr, out, nullptr, nullptr, nullptr);
}

// Round 5
// 671.299 us; speedup vs baseline: 1.1179x; 1.0114x over previous
//
#include <hip/hip_runtime.h>
#include <hip/hip_bf16.h>
#include <cmath>

#define Bn 2
#define Sn 2048
#define En 2048
#define Hn 16
#define HDn 128
#define Mn (Bn*Sn)
#define NORMS2 92.33248261689366f   /* 64 * log2(e) : softmax done in base 2 */

typedef __attribute__((ext_vector_type(8))) short short8;
typedef __attribute__((ext_vector_type(4))) float f32x4;

__device__ __forceinline__ short f2bf(float x) {
    __hip_bfloat16 h = __float2bfloat16(x);
    return *reinterpret_cast<short*>(&h);
}
__device__ __forceinline__ float bf2f(short s) {
    __hip_bfloat16 h = *reinterpret_cast<__hip_bfloat16*>(&s);
    return __bfloat162float(h);
}
__device__ __forceinline__ void gl_lds16(const void* g, void* l) {
    __builtin_amdgcn_global_load_lds(
        (const __attribute__((address_space(1))) unsigned int*)g,
        (__attribute__((address_space(3))) unsigned int*)l, 16, 0, 0);
}

#if __has_builtin(__builtin_amdgcn_exp2f)
#define EXP2(x) __builtin_amdgcn_exp2f(x)
#else
#define EXP2(x) exp2f(x)
#endif

template<int CTRL>
__device__ __forceinline__ float dppf(float x) {
    int r = __builtin_amdgcn_update_dpp(0, __builtin_bit_cast(int, x), CTRL, 0xf, 0xf, true);
    return __builtin_bit_cast(float, r);
}
__device__ __forceinline__ float redmax16(float x) {
    x = fmaxf(x, dppf<0xB1>(x));   // quad_perm xor1
    x = fmaxf(x, dppf<0x4E>(x));   // quad_perm xor2
    x = fmaxf(x, dppf<0x141>(x));  // row_half_mirror xor7
    x = fmaxf(x, dppf<0x140>(x));  // row_mirror xor15
    return x;
}
__device__ __forceinline__ float redsum16(float x) {
    x += dppf<0xB1>(x);
    x += dppf<0x4E>(x);
    x += dppf<0x141>(x);
    x += dppf<0x140>(x);
    return x;
}

// ---- sin/cos tables in fp64 ----
static __global__ void rope_table_kernel(float* __restrict__ sinT, float* __restrict__ cosT) {
    int i = blockIdx.x * 256 + threadIdx.x;
    int t = i >> 6, f = i & 63;
    double inv = pow(10000.0, -(double)(2 * f) / (double)HDn);
    double ang = (double)t * inv;
    sinT[i] = (float)sin(ang);
    cosT[i] = (float)cos(ang);
}

// ---- split fp32 -> bf16 hi/lo ----
static __global__ void split_x_kernel(const float* __restrict__ X,
                                      short* __restrict__ Xhi, short* __restrict__ Xlo) {
    int i = (blockIdx.x * 256 + threadIdx.x) * 4;
    float4 x = *(const float4*)&X[i];
    short4 hi, lo;
    hi.x = f2bf(x.x); lo.x = f2bf(x.x - bf2f(hi.x));
    hi.y = f2bf(x.y); lo.y = f2bf(x.y - bf2f(hi.y));
    hi.z = f2bf(x.z); lo.z = f2bf(x.z - bf2f(hi.z));
    hi.w = f2bf(x.w); lo.w = f2bf(x.w - bf2f(hi.w));
    *(short4*)&Xhi[i] = hi;
    *(short4*)&Xlo[i] = lo;
}

// ---- mask fp32 -> bf16, pre-scaled by NORMS2 (exact for zero mask) ----
static __global__ void maskconv_kernel(const float* __restrict__ M, short* __restrict__ MB) {
    int i = (blockIdx.x * 256 + threadIdx.x) * 4;
    float4 m = *(const float4*)&M[i];
    short4 o;
    o.x = f2bf(m.x * NORMS2); o.y = f2bf(m.y * NORMS2);
    o.z = f2bf(m.z * NORMS2); o.w = f2bf(m.w * NORMS2);
    *(short4*)&MB[i] = o;
}

// ---- transpose all 4 weights in one dispatch (z selects) ----
static __global__ __launch_bounds__(256) void wtrans4_kernel(
        const float* __restrict__ Wq, const float* __restrict__ Wk,
        const float* __restrict__ Wv, const float* __restrict__ Wo,
        short* __restrict__ QKh, short* __restrict__ QKl,
        short* __restrict__ VT, short* __restrict__ OT) {
    __shared__ float tile[32][33];
    const int z = blockIdx.z;
    const float* W = (z == 0) ? Wq : (z == 1) ? Wk : (z == 2) ? Wv : Wo;
    short* Th = (z <= 1) ? QKh : (z == 2) ? VT : OT;
    const int rowoff = (z == 1) ? 2048 : 0;
    const bool split = (z <= 1);
    int tx = threadIdx.x & 31, ty = threadIdx.x >> 5;
    int k0 = blockIdx.y * 32, n0 = blockIdx.x * 32;
    #pragma unroll
    for (int i = 0; i < 4; ++i)
        tile[ty + i * 8][tx] = W[(size_t)(k0 + ty + i * 8) * En + n0 + tx];
    __syncthreads();
    #pragma unroll
    for (int i = 0; i < 4; ++i) {
        float v = tile[tx][ty + i * 8];
        size_t idx = (size_t)(rowoff + n0 + ty + i * 8) * En + k0 + tx;
        short hv = f2bf(v);
        Th[idx] = hv;
        if (split) QKl[idx] = f2bf(v - bf2f(hv));
    }
}

// ---- MFMA GEMM: C[M][N] = A[M][K] * BT[N][K]^T, 128x128 tile, BK=32 ----
// v2: K-tile LDS DOUBLE-BUFFER, stage-early / drain-late (flash9 recipe):
// stage tile k+1 into buf^1 BEFORE computing tile k, ONE __syncthreads per
// K-step at the end. The implicit vmcnt(0) drain at that barrier hits loads
// issued a full compute phase (96/32 MFMAs) earlier -> ~free. Numerics
// identical to v1 (same MFMA chains/order).
// NPROD=3: split products (hi*hi + hi*lo + lo*hi)
// OUTMODE=0: fp32 row-major -> Cf
// OUTMODE=1: bf16 V^T [(b,h,d)][s] via LDS transpose (coalesced) -> Cbt
// OUTMODE=3: packed (hi<<16|lo) int32 row-major, cols<2048 -> Qpk else Kpk
template<int NPROD, int OUTMODE>
static __global__ __launch_bounds__(256) void gemm_kernel(
        const short* __restrict__ Ahi, const short* __restrict__ Alo,
        const short* __restrict__ Bhi, const short* __restrict__ Blo,
        float* __restrict__ Cf, short* __restrict__ Cbt,
        int* __restrict__ Qpk, int* __restrict__ Kpk) {
    __shared__ short As_hi[2 * 128 * 32];
    __shared__ short Bs_hi[2 * 128 * 32];
    __shared__ short As_lo[NPROD == 3 ? 2 * 128 * 32 : 8];
    __shared__ short Bs_lo[NPROD == 3 ? 2 * 128 * 32 : 8];
    __shared__ short Ts[OUTMODE == 1 ? 128 * 136 : 8];

    const int tid = threadIdx.x;
    const int w = tid >> 6, l = tid & 63;
    const int quad = l >> 4, l15 = l & 15;
    const int wr = (w >> 1) * 64, wc = (w & 1) * 64;
    const int row0 = blockIdx.y * 128, col0 = blockIdx.x * 128;

    const int off0 = tid * 16;
    const int r_a = off0 >> 6;
    const int kb = (off0 & 63) >> 1;

    // stage one 128x32 K-tile (all planes) into buffer at short-offset bs
    auto STAGE = [&](int bs, int kk) {
        const short* ap = Ahi + (size_t)(row0 + r_a) * En + kk + kb;
        const short* bp = Bhi + (size_t)(col0 + r_a) * En + kk + kb;
        gl_lds16(ap,           &As_hi[bs + off0 / 2]);
        gl_lds16(ap + 64 * En, &As_hi[bs + (off0 + 4096) / 2]);
        gl_lds16(bp,           &Bs_hi[bs + off0 / 2]);
        gl_lds16(bp + 64 * En, &Bs_hi[bs + (off0 + 4096) / 2]);
        if constexpr (NPROD == 3) {
            const short* ap2 = Alo + (size_t)(row0 + r_a) * En + kk + kb;
            const short* bp2 = Blo + (size_t)(col0 + r_a) * En + kk + kb;
            gl_lds16(ap2,           &As_lo[bs + off0 / 2]);
            gl_lds16(ap2 + 64 * En, &As_lo[bs + (off0 + 4096) / 2]);
            gl_lds16(bp2,           &Bs_lo[bs + off0 / 2]);
            gl_lds16(bp2 + 64 * En, &Bs_lo[bs + (off0 + 4096) / 2]);
        }
    };

    f32x4 acc[4][4];
    #pragma unroll
    for (int i = 0; i < 4; ++i)
        #pragma unroll
        for (int j = 0; j < 4; ++j) acc[i][j] = f32x4{0.f, 0.f, 0.f, 0.f};

    STAGE(0, 0);
    __syncthreads();   // prologue drain (only one that exposes latency)

    for (int k0 = 0; k0 < En; k0 += 32) {
        const int cb = ((k0 >> 5) & 1) * 4096;   // current buffer (shorts)
        const int nb = cb ^ 4096;                // next buffer
        if (k0 + 32 < En) STAGE(nb, k0 + 32);    // prefetch next K-tile

        short8 bhf[4], blf[4];
        #pragma unroll
        for (int ni = 0; ni < 4; ++ni) {
            bhf[ni] = *(const short8*)&Bs_hi[cb + (wc + ni * 16 + l15) * 32 + quad * 8];
            if constexpr (NPROD == 3)
                blf[ni] = *(const short8*)&Bs_lo[cb + (wc + ni * 16 + l15) * 32 + quad * 8];
        }
        #pragma unroll
        for (int mi = 0; mi < 4; ++mi) {
            short8 ahf = *(const short8*)&As_hi[cb + (wr + mi * 16 + l15) * 32 + quad * 8];
            short8 alf;
            if constexpr (NPROD == 3)
                alf = *(const short8*)&As_lo[cb + (wr + mi * 16 + l15) * 32 + quad * 8];
            #pragma unroll
            for (int ni = 0; ni < 4; ++ni) {
                acc[mi][ni] = __builtin_amdgcn_mfma_f32_16x16x32_bf16(ahf, bhf[ni], acc[mi][ni], 0, 0, 0);
                if constexpr (NPROD == 3) {
                    acc[mi][ni] = __builtin_amdgcn_mfma_f32_16x16x32_bf16(ahf, blf[ni], acc[mi][ni], 0, 0, 0);
                    acc[mi][ni] = __builtin_amdgcn_mfma_f32_16x16x32_bf16(alf, bhf[ni], acc[mi][ni], 0, 0, 0);
                }
            }
        }
        // ONE barrier per K-step: this iter's prefetch (into nb) becomes
        // visible, and cb is free to be overwritten next iteration.
        __syncthreads();
    }

    if constexpr (OUTMODE == 0) {
        #pragma unroll
        for (int mi = 0; mi < 4; ++mi)
            #pragma unroll
            for (int ni = 0; ni < 4; ++ni) {
                int r = row0 + wr + mi * 16 + quad * 4;
                int c = col0 + wc + ni * 16 + l15;
                #pragma unroll
                for (int reg = 0; reg < 4; ++reg)
                    Cf[(size_t)(r + reg) * En + c] = acc[mi][ni][reg];
            }
    } else if constexpr (OUTMODE == 1) {
        // LDS transpose -> coalesced V^T stores
        #pragma unroll
        for (int mi = 0; mi < 4; ++mi)
            #pragma unroll
            for (int ni = 0; ni < 4; ++ni) {
                int dl = wc + ni * 16 + l15;            // local col (d)
                int sl = wr + mi * 16 + quad * 4;       // local row (s)
                #pragma unroll
                for (int reg = 0; reg < 4; ++reg)
                    Ts[dl * 136 + sl + reg] = f2bf(acc[mi][ni][reg]);
            }
        __syncthreads();
        int dl = tid >> 1, s0 = (tid & 1) * 64;
        int b = row0 >> 11, h = col0 >> 7;
        size_t gbase = ((size_t)(b * Hn + h) * HDn + dl) * Sn + (row0 & (Sn - 1)) + s0;
        #pragma unroll
        for (int k = 0; k < 8; ++k) {
            short8 vv = *(const short8*)&Ts[dl * 136 + s0 + k * 8];
            *(short8*)&Cbt[gbase + k * 8] = vv;
        }
    } else {
        int* dst = (col0 >= 2048) ? Kpk : Qpk;
        const int cb = col0 & 2047;
        #pragma unroll
        for (int mi = 0; mi < 4; ++mi)
            #pragma unroll
            for (int ni = 0; ni < 4; ++ni) {
                int r = row0 + wr + mi * 16 + quad * 4;
                int c = cb + wc + ni * 16 + l15;
                #pragma unroll
                for (int reg = 0; reg < 4; ++reg) {
                    float v = acc[mi][ni][reg];
                    short hh = f2bf(v);
                    short ll = f2bf(v - bf2f(hh));
                    dst[(size_t)(r + reg) * 2048 + c] =
                        ((int)(unsigned short)hh << 16) | (unsigned short)ll;
                }
            }
    }
}

// ---- RoPE on packed (hi<<16|lo) int32 -> split bf16 planes ----
static __global__ void rope_pk_kernel(const int* __restrict__ Pre,
        short* __restrict__ Yh, short* __restrict__ Yl,
        const float* __restrict__ sinT, const float* __restrict__ cosT) {
    int p = blockIdx.x * 256 + threadIdx.x;       // < 2^21 ; 4 elements/thread
    int u = p & 511;
    int t = (p >> 9) & (Sn - 1);
    int b = p >> 20;
    int tsrc; float sgn;
    if (t < Sn / 2) { tsrc = 2 * t + 1; sgn = -1.f; }
    else            { tsrc = 2 * (t - Sn / 2); sgn = 1.f; }
    int f0 = (2 * u) & 63, f1 = (2 * u + 1) & 63;
    float sv0 = sinT[(t << 6) + f0], cv0 = cosT[(t << 6) + f0];
    float sv1 = sinT[(t << 6) + f1], cv1 = cosT[(t << 6) + f1];
    size_t rt = ((size_t)(b * Sn + t)) * 512 + u;     // int4 units
    size_t rs = ((size_t)(b * Sn + tsrc)) * 512 + u;
    int4 xt = ((const int4*)Pre)[rt];
    int4 xs = ((const int4*)Pre)[rs];
    auto up = [](int v) -> float {
        return bf2f((short)(v >> 16)) + bf2f((short)(v & 0xffff));
    };
    float x0 = up(xt.x), x1 = up(xt.y), x2 = up(xt.z), x3 = up(xt.w);
    float s0 = up(xs.x), s1 = up(xs.y), s2 = up(xs.z), s3 = up(xs.w);
    float y0 = x0 * cv0 + sgn * s0 * sv0;
    float y1 = x1 * cv0 + sgn * s1 * sv0;
    float y2 = x2 * cv1 + sgn * s2 * sv1;
    float y3 = x3 * cv1 + sgn * s3 * sv1;
    short4 hi, lo;
    hi.x = f2bf(y0); lo.x = f2bf(y0 - bf2f(hi.x));
    hi.y = f2bf(y1); lo.y = f2bf(y1 - bf2f(hi.y));
    hi.z = f2bf(y2); lo.z = f2bf(y2 - bf2f(hi.z));
    hi.w = f2bf(y3); lo.w = f2bf(y3 - bf2f(hi.w));
    size_t o = ((size_t)(b * Sn + t)) * En + 4 * u;
    *(short4*)&Yh[o] = hi;
    *(short4*)&Yl[o] = lo;
}

// ---- MFMA flash attention v9 ----
// 512 threads (8 waves), 128 q-rows/block, 64-key tiles; flash5 per-tile
// compute (identical numerics) + K/V LDS DOUBLE-BUFFER with stage-early /
// drain-late: stage tile j+1 into buf^1 at top of iter, compute tile j from
// buf, ONE __syncthreads per tile at the END. The implicit vmcnt(0) drain at
// that barrier hits loads issued a full compute-phase earlier -> ~free.
// LDS (shorts): buf0 [0,24576): K-hi/K-lo/V each 8192
//               buf1 [24576,49152): same layout
//               P    [49152,59392): 8 waves x 1280
// Q staged transiently in [0,32768) before buffers are first used.
// 118784 B -> 1 block/CU (8 waves).
static __global__ __launch_bounds__(512, 2) void flash9_kernel(
        const short* __restrict__ Qhi, const short* __restrict__ Qlo,
        const short* __restrict__ Khi, const short* __restrict__ Klo,
        const short* __restrict__ Vt, const short* __restrict__ maskB,
        short* __restrict__ AO) {
    __shared__ short lds0[59392];

    const int tid = threadIdx.x;
    const int w = tid >> 6, l = tid & 63;
    const int quad = l >> 4, l15 = l & 15;
    const int n = blockIdx.x;
    const int bh = (n & 7) * 4 + ((n >> 3) & 3);   // heads grouped per XCD
    const int qt = n >> 5;                          // 32 consecutive blocks share mask rows
    const int b = bh >> 4, h = bh & 15;
    const int r0 = qt * 128;
    const size_t qkbase = (size_t)b * Sn * En + (size_t)h * HDn;
    const int psb = 49152 + w * 1280;

    // ---- stage Q (transient, overlaps buffer region) ----
    #pragma unroll
    for (int c = 0; c < 4; ++c) {
        int off = tid * 16 + c * 8192;
        int row = off >> 8;
        int gp = (off >> 4) & 15;
        int gl = gp ^ (row & 7);
        size_t gidx = qkbase + (size_t)(r0 + row) * En + gl * 8;
        gl_lds16(Qhi + gidx, &lds0[off / 2]);
        gl_lds16(Qlo + gidx, &lds0[16384 + off / 2]);
    }
    __syncthreads();
    short8 qh[4], ql[4];
    {
        int row = 16 * w + l15;
        #pragma unroll
        for (int kc = 0; kc < 4; ++kc) {
            int gp = (kc * 4 + quad) ^ (row & 7);
            qh[kc] = *(const short8*)&lds0[row * 128 + gp * 8];
            ql[kc] = *(const short8*)&lds0[16384 + row * 128 + gp * 8];
        }
    }
    __syncthreads();   // all waves done reading Q before buffers are written

    // ---- staging helper: K hi/lo + V for key-tile jj into buffer at bbase ----
    auto STAGE = [&](int bbase, int jj) {
        #pragma unroll
        for (int c = 0; c < 2; ++c) {          // K hi/lo (64 rows x 256 B)
            int off = tid * 16 + c * 8192;     // [0,16384) bytes
            int row = off >> 8;                // 0..63
            int gp = (off >> 4) & 15;
            int gl = gp ^ (row & 7);
            size_t gidx = qkbase + (size_t)(jj + row) * En + gl * 8;
            gl_lds16(Khi + gidx, &lds0[bbase + off / 2]);
            gl_lds16(Klo + gidx, &lds0[bbase + 8192 + off / 2]);
        }
        #pragma unroll
        for (int c = 0; c < 2; ++c) {          // V (128 d-rows x 128 B)
            int off = tid * 16 + c * 8192;     // [0,16384) bytes
            int vrow = off >> 7;               // 0..127
            int vgp = (off >> 4) & 7;
            int vgl = vgp ^ (vrow & 7);
            size_t vidx = ((size_t)bh * HDn + vrow) * Sn + jj + vgl * 8;
            gl_lds16(Vt + vidx, &lds0[bbase + 16384 + off / 2]);
        }
    };

    STAGE(0, 0);          // tile 0 -> buf0
    __syncthreads();      // only prologue drain that exposes latency

    f32x4 O[8];
    #pragma unroll
    for (int di = 0; di < 8; ++di) O[di] = f32x4{0.f, 0.f, 0.f, 0.f};
    float m_prev[4] = {-INFINITY, -INFINITY, -INFINITY, -INFINITY};
    float l_run[4] = {0.f, 0.f, 0.f, 0.f};
    const int qrow_base = r0 + 16 * w + quad * 4;

    for (int j0 = 0; j0 < Sn; j0 += 64) {
        const int bb = ((j0 >> 6) & 1) * 24576;   // current buffer base
        const int nb = bb ^ 24576;                // next buffer base

        float mv[4][4];                        // bf16 mask prefetch (pre-scaled)
        #pragma unroll
        for (int ni = 0; ni < 4; ++ni)
            #pragma unroll
            for (int reg = 0; reg < 4; ++reg)
                mv[ni][reg] = bf2f(maskB[(size_t)(qrow_base + reg) * Sn + j0 + ni * 16 + l15]);

        if (j0 + 64 < Sn) STAGE(nb, j0 + 64);  // prefetch next tile (drained at end-of-iter barrier)

        // ---- QK^T (3 split products) from buf[bb] ----
        f32x4 p[4];
        #pragma unroll
        for (int ni = 0; ni < 4; ++ni) p[ni] = f32x4{0.f, 0.f, 0.f, 0.f};
        #pragma unroll
        for (int ni = 0; ni < 4; ++ni) {
            int col = ni * 16 + l15;
            #pragma unroll
            for (int kc = 0; kc < 4; ++kc) {
                int gp = (kc * 4 + quad) ^ (col & 7);
                short8 kh = *(const short8*)&lds0[bb + col * 128 + gp * 8];
                short8 kl = *(const short8*)&lds0[bb + 8192 + col * 128 + gp * 8];
                p[ni] = __builtin_amdgcn_mfma_f32_16x16x32_bf16(qh[kc], kh, p[ni], 0, 0, 0);
                p[ni] = __builtin_amdgcn_mfma_f32_16x16x32_bf16(qh[kc], kl, p[ni], 0, 0, 0);
                p[ni] = __builtin_amdgcn_mfma_f32_16x16x32_bf16(ql[kc], kh, p[ni], 0, 0, 0);
            }
        }

        // ---- softmax in base 2, DPP reductions (flash5 math, unchanged) ----
        float rm[4] = {-INFINITY, -INFINITY, -INFINITY, -INFINITY};
        #pragma unroll
        for (int ni = 0; ni < 4; ++ni)
            #pragma unroll
            for (int reg = 0; reg < 4; ++reg) {
                float v = fmaf(p[ni][reg], NORMS2, mv[ni][reg]);
                p[ni][reg] = v;
                rm[reg] = fmaxf(rm[reg], v);
            }
        #pragma unroll
        for (int reg = 0; reg < 4; ++reg) rm[reg] = redmax16(rm[reg]);
        float al[4], mn[4], rs[4];
        #pragma unroll
        for (int reg = 0; reg < 4; ++reg) {
            mn[reg] = fmaxf(m_prev[reg], rm[reg]);
            al[reg] = EXP2(m_prev[reg] - mn[reg]);
            rs[reg] = 0.f;
        }
        #pragma unroll
        for (int ni = 0; ni < 4; ++ni)
            #pragma unroll
            for (int reg = 0; reg < 4; ++reg) {
                float pe = EXP2(p[ni][reg] - mn[reg]);
                rs[reg] += pe;
                lds0[psb + (quad * 4 + reg) * 80 + ((ni ^ quad) << 4) + l15] = f2bf(pe);
            }
        #pragma unroll
        for (int reg = 0; reg < 4; ++reg) rs[reg] = redsum16(rs[reg]);
        #pragma unroll
        for (int reg = 0; reg < 4; ++reg) {
            l_run[reg] = l_run[reg] * al[reg] + rs[reg];
            m_prev[reg] = mn[reg];
        }
        #pragma unroll
        for (int di = 0; di < 8; ++di)
            #pragma unroll
            for (int reg = 0; reg < 4; ++reg)
                O[di][reg] *= al[reg];

        short8 pa[2];
        #pragma unroll
        for (int kc2 = 0; kc2 < 2; ++kc2) {
            int g = kc2 * 2 + (quad >> 1);
            int gs = g ^ (l15 >> 2);
            pa[kc2] = *(const short8*)&lds0[psb + l15 * 80 + (gs << 4) + (quad & 1) * 8];
        }

        // ---- PV from buf[bb] ----
        #pragma unroll
        for (int di = 0; di < 8; ++di) {
            int d = di * 16 + l15;
            #pragma unroll
            for (int kc2 = 0; kc2 < 2; ++kc2) {
                int gp = (kc2 * 4 + quad) ^ (d & 7);
                short8 vb = *(const short8*)&lds0[bb + 16384 + d * 64 + gp * 8];
                O[di] = __builtin_amdgcn_mfma_f32_16x16x32_bf16(pa[kc2], vb, O[di], 0, 0, 0);
            }
        }

        // ONE barrier per tile: prev-iter prefetch now visible to all waves,
        // and buf[bb] is free to be overwritten next iteration.
        __syncthreads();
    }

    float inv[4];
    #pragma unroll
    for (int reg = 0; reg < 4; ++reg) inv[reg] = 1.0f / l_run[reg];
    #pragma unroll
    for (int di = 0; di < 8; ++di)
        #pragma unroll
        for (int reg = 0; reg < 4; ++reg) {
            size_t idx = ((size_t)b * Sn + qrow_base + reg) * En + h * HDn + di * 16 + l15;
            AO[idx] = f2bf(O[di][reg] * inv[reg]);
        }
}

extern "C" void kernel_launch(void* const* d_in, const int* in_sizes, int n_in,
                              void* d_out, int out_size, void* d_ws, size_t ws_size,
                              hipStream_t stream) {
    const float* inputs = (const float*)d_in[0];
    const float* mask   = (const float*)d_in[1];
    const float* wq     = (const float*)d_in[2];
    const float* wk     = (const float*)d_in[3];
    const float* wv     = (const float*)d_in[4];
    const float* wo     = (const float*)d_in[5];
    float* out = (float*)d_out;
    (void)in_sizes; (void)n_in; (void)out_size; (void)ws_size;

    char* W8 = (char*)d_ws;
    float* sinT  = (float*)(W8 + 0);
    float* cosT  = (float*)(W8 + 524288);
    short* Xhi   = (short*)(W8 + 1048576);
    short* Xlo   = (short*)(W8 + 17825792);
    short* maskB = (short*)(W8 + 34603008);
    short* WqkTh = (short*)(W8 + 42991616);
    short* WqkTl = (short*)(W8 + 59768832);
    short* WvT   = (short*)(W8 + 76546048);
    short* WoT   = (short*)(W8 + 84934656);
    int*   Qpk   = (int*)(W8 + 93323264);
    int*   Kpk   = (int*)(W8 + 126877696);
    // aliases (lifetimes disjoint; ordering enforced by dispatch sequence):
    short* Qhi = WqkTh;                        // rope-Q out over W-qk (dead after QK-GEMM)
    short* Qlo = WqkTl;
    short* Khi = (short*)(W8 + 93323264);      // rope-K out over Qpk (dead after rope-Q)
    short* Klo = (short*)(W8 + 110100480);
    short* Vt  = (short*)(W8 + 126877696);     // V^T over Kpk (dead after rope-K)
    short* AO  = Xhi;                          // flash out over X-hi (dead after V-GEMM)

    rope_table_kernel<<<512, 256, 0, stream>>>(sinT, cosT);
    split_x_kernel<<<8192, 256, 0, stream>>>(inputs, Xhi, Xlo);
    maskconv_kernel<<<4096, 256, 0, stream>>>(mask, maskB);
    wtrans4_kernel<<<dim3(64, 64, 4), 256, 0, stream>>>(wq, wk, wv, wo,
                                                        WqkTh, WqkTl, WvT, WoT);

    gemm_kernel<3, 3><<<dim3(32, 32), 256, 0, stream>>>(
        Xhi, Xlo, WqkTh, WqkTl, nullptr, nullptr, Qpk, Kpk);
    rope_pk_kernel<<<8192, 256, 0, stream>>>(Qpk, Qhi, Qlo, sinT, cosT);
    rope_pk_kernel<<<8192, 256, 0, stream>>>(Kpk, Khi, Klo, sinT, cosT);
    gemm_kernel<1, 1><<<dim3(16, 32), 256, 0, stream>>>(
        Xhi, nullptr, WvT, nullptr, nullptr, Vt, nullptr, nullptr);

    flash9_kernel<<<512, 512, 0, stream>>>(Qhi, Qlo, Khi, Klo, Vt, maskB, AO);

    gemm_kernel<1, 0><<<dim3(16, 32), 256, 0, stream>>>(
        AO, nullptr, WoT, nullptr, out, nullptr, nullptr, nullptr);
}

// Round 6
// 662.423 us; speedup vs baseline: 1.1329x; 1.0134x over previous
//
#include <hip/hip_runtime.h>
#include <hip/hip_bf16.h>
#include <cmath>

#define Bn 2
#define Sn 2048
#define En 2048
#define Hn 16
#define HDn 128
#define Mn (Bn*Sn)
#define NORMS2 92.33248261689366f   /* 64 * log2(e) : softmax done in base 2 */

typedef __attribute__((ext_vector_type(8))) short short8;
typedef __attribute__((ext_vector_type(4))) float f32x4;

__device__ __forceinline__ short f2bf(float x) {
    __hip_bfloat16 h = __float2bfloat16(x);
    return *reinterpret_cast<short*>(&h);
}
__device__ __forceinline__ float bf2f(short s) {
    __hip_bfloat16 h = *reinterpret_cast<__hip_bfloat16*>(&s);
    return __bfloat162float(h);
}
__device__ __forceinline__ void gl_lds16(const void* g, void* l) {
    __builtin_amdgcn_global_load_lds(
        (const __attribute__((address_space(1))) unsigned int*)g,
        (__attribute__((address_space(3))) unsigned int*)l, 16, 0, 0);
}

#if __has_builtin(__builtin_amdgcn_exp2f)
#define EXP2(x) __builtin_amdgcn_exp2f(x)
#else
#define EXP2(x) exp2f(x)
#endif

template<int CTRL>
__device__ __forceinline__ float dppf(float x) {
    int r = __builtin_amdgcn_update_dpp(0, __builtin_bit_cast(int, x), CTRL, 0xf, 0xf, true);
    return __builtin_bit_cast(float, r);
}
__device__ __forceinline__ float redmax16(float x) {
    x = fmaxf(x, dppf<0xB1>(x));   // quad_perm xor1
    x = fmaxf(x, dppf<0x4E>(x));   // quad_perm xor2
    x = fmaxf(x, dppf<0x141>(x));  // row_half_mirror xor7
    x = fmaxf(x, dppf<0x140>(x));  // row_mirror xor15
    return x;
}
__device__ __forceinline__ float redsum16(float x) {
    x += dppf<0xB1>(x);
    x += dppf<0x4E>(x);
    x += dppf<0x141>(x);
    x += dppf<0x140>(x);
    return x;
}

// ---- sin/cos tables in fp64 ----
static __global__ void rope_table_kernel(float* __restrict__ sinT, float* __restrict__ cosT) {
    int i = blockIdx.x * 256 + threadIdx.x;
    int t = i >> 6, f = i & 63;
    double inv = pow(10000.0, -(double)(2 * f) / (double)HDn);
    double ang = (double)t * inv;
    sinT[i] = (float)sin(ang);
    cosT[i] = (float)cos(ang);
}

// ---- split fp32 -> bf16 hi/lo ----
static __global__ void split_x_kernel(const float* __restrict__ X,
                                      short* __restrict__ Xhi, short* __restrict__ Xlo) {
    int i = (blockIdx.x * 256 + threadIdx.x) * 4;
    float4 x = *(const float4*)&X[i];
    short4 hi, lo;
    hi.x = f2bf(x.x); lo.x = f2bf(x.x - bf2f(hi.x));
    hi.y = f2bf(x.y); lo.y = f2bf(x.y - bf2f(hi.y));
    hi.z = f2bf(x.z); lo.z = f2bf(x.z - bf2f(hi.z));
    hi.w = f2bf(x.w); lo.w = f2bf(x.w - bf2f(hi.w));
    *(short4*)&Xhi[i] = hi;
    *(short4*)&Xlo[i] = lo;
}

// ---- mask fp32 -> bf16, pre-scaled by NORMS2 (exact for zero mask) ----
static __global__ void maskconv_kernel(const float* __restrict__ M, short* __restrict__ MB) {
    int i = (blockIdx.x * 256 + threadIdx.x) * 4;
    float4 m = *(const float4*)&M[i];
    short4 o;
    o.x = f2bf(m.x * NORMS2); o.y = f2bf(m.y * NORMS2);
    o.z = f2bf(m.z * NORMS2); o.w = f2bf(m.w * NORMS2);
    *(short4*)&MB[i] = o;
}

// ---- transpose all 4 weights in one dispatch (z selects) ----
static __global__ __launch_bounds__(256) void wtrans4_kernel(
        const float* __restrict__ Wq, const float* __restrict__ Wk,
        const float* __restrict__ Wv, const float* __restrict__ Wo,
        short* __restrict__ QKh, short* __restrict__ QKl,
        short* __restrict__ VT, short* __restrict__ OT) {
    __shared__ float tile[32][33];
    const int z = blockIdx.z;
    const float* W = (z == 0) ? Wq : (z == 1) ? Wk : (z == 2) ? Wv : Wo;
    short* Th = (z <= 1) ? QKh : (z == 2) ? VT : OT;
    const int rowoff = (z == 1) ? 2048 : 0;
    const bool split = (z <= 1);
    int tx = threadIdx.x & 31, ty = threadIdx.x >> 5;
    int k0 = blockIdx.y * 32, n0 = blockIdx.x * 32;
    #pragma unroll
    for (int i = 0; i < 4; ++i)
        tile[ty + i * 8][tx] = W[(size_t)(k0 + ty + i * 8) * En + n0 + tx];
    __syncthreads();
    #pragma unroll
    for (int i = 0; i < 4; ++i) {
        float v = tile[tx][ty + i * 8];
        size_t idx = (size_t)(rowoff + n0 + ty + i * 8) * En + k0 + tx;
        short hv = f2bf(v);
        Th[idx] = hv;
        if (split) QKl[idx] = f2bf(v - bf2f(hv));
    }
}

// ---- MFMA GEMM: C[M][N] = A[M][K] * BT[N][K]^T, 128x128 tile, BK=32 ----
// v3: dbuf + COUNTED vmcnt (T4): STAGE(next) -> s_waitcnt vmcnt(8) (waits only
// the PREVIOUS iter's loads; this iter's 8 stay in flight across the barrier)
// -> s_barrier -> compute -> bare s_barrier (no drain; cb ds_reads are all
// consumed by MFMAs before the barrier). v2's __syncthreads drained the
// just-issued prefetch every K-step (vmcnt(0)) -> exposed the L2 delivery
// tail (~485 cyc vs ~310-620 cyc compute). Loop has NO other VMEM ops, so
// the count is exact. Numerics identical.
// NPROD=3: split products (hi*hi + hi*lo + lo*hi)
// OUTMODE=0: fp32 row-major -> Cf
// OUTMODE=1: bf16 V^T [(b,h,d)][s] via LDS transpose (coalesced) -> Cbt
// OUTMODE=3: packed (hi<<16|lo) int32 row-major, cols<2048 -> Qpk else Kpk
template<int NPROD, int OUTMODE>
static __global__ __launch_bounds__(256) void gemm_kernel(
        const short* __restrict__ Ahi, const short* __restrict__ Alo,
        const short* __restrict__ Bhi, const short* __restrict__ Blo,
        float* __restrict__ Cf, short* __restrict__ Cbt,
        int* __restrict__ Qpk, int* __restrict__ Kpk) {
    __shared__ short As_hi[2 * 128 * 32];
    __shared__ short Bs_hi[2 * 128 * 32];
    __shared__ short As_lo[NPROD == 3 ? 2 * 128 * 32 : 8];
    __shared__ short Bs_lo[NPROD == 3 ? 2 * 128 * 32 : 8];
    __shared__ short Ts[OUTMODE == 1 ? 128 * 136 : 8];

    const int tid = threadIdx.x;
    const int w = tid >> 6, l = tid & 63;
    const int quad = l >> 4, l15 = l & 15;
    const int wr = (w >> 1) * 64, wc = (w & 1) * 64;
    const int row0 = blockIdx.y * 128, col0 = blockIdx.x * 128;

    const int off0 = tid * 16;
    const int r_a = off0 >> 6;
    const int kb = (off0 & 63) >> 1;

    // stage one 128x32 K-tile (all planes) into buffer at short-offset bs
    // NPROD==3: 8 gl_lds per call; NPROD==1: 4 gl_lds per call.
    auto STAGE = [&](int bs, int kk) {
        const short* ap = Ahi + (size_t)(row0 + r_a) * En + kk + kb;
        const short* bp = Bhi + (size_t)(col0 + r_a) * En + kk + kb;
        gl_lds16(ap,           &As_hi[bs + off0 / 2]);
        gl_lds16(ap + 64 * En, &As_hi[bs + (off0 + 4096) / 2]);
        gl_lds16(bp,           &Bs_hi[bs + off0 / 2]);
        gl_lds16(bp + 64 * En, &Bs_hi[bs + (off0 + 4096) / 2]);
        if constexpr (NPROD == 3) {
            const short* ap2 = Alo + (size_t)(row0 + r_a) * En + kk + kb;
            const short* bp2 = Blo + (size_t)(col0 + r_a) * En + kk + kb;
            gl_lds16(ap2,           &As_lo[bs + off0 / 2]);
            gl_lds16(ap2 + 64 * En, &As_lo[bs + (off0 + 4096) / 2]);
            gl_lds16(bp2,           &Bs_lo[bs + off0 / 2]);
            gl_lds16(bp2 + 64 * En, &Bs_lo[bs + (off0 + 4096) / 2]);
        }
    };

    f32x4 acc[4][4];
    #pragma unroll
    for (int i = 0; i < 4; ++i)
        #pragma unroll
        for (int j = 0; j < 4; ++j) acc[i][j] = f32x4{0.f, 0.f, 0.f, 0.f};

    STAGE(0, 0);
    __syncthreads();   // prologue: full drain once (tile 0 visible)

    for (int k0 = 0; k0 < En; k0 += 32) {
        const int cb = ((k0 >> 5) & 1) * 4096;   // current buffer (shorts)
        const int nb = cb ^ 4096;                // next buffer
        if (k0 + 32 < En) {
            STAGE(nb, k0 + 32);                  // prefetch stays in flight
            // wait ONLY the previous iter's loads (the cb about to be read):
            asm volatile("s_waitcnt vmcnt(%0)" :: "i"(NPROD == 3 ? 8 : 4) : "memory");
        } else {
            asm volatile("s_waitcnt vmcnt(0)" ::: "memory");  // last tile: drain
        }
        __builtin_amdgcn_sched_barrier(0);       // rule #18: pin order
        __builtin_amdgcn_s_barrier();            // all waves' cb loads complete

        short8 bhf[4], blf[4];
        #pragma unroll
        for (int ni = 0; ni < 4; ++ni) {
            bhf[ni] = *(const short8*)&Bs_hi[cb + (wc + ni * 16 + l15) * 32 + quad * 8];
            if constexpr (NPROD == 3)
                blf[ni] = *(const short8*)&Bs_lo[cb + (wc + ni * 16 + l15) * 32 + quad * 8];
        }
        #pragma unroll
        for (int mi = 0; mi < 4; ++mi) {
            short8 ahf = *(const short8*)&As_hi[cb + (wr + mi * 16 + l15) * 32 + quad * 8];
            short8 alf;
            if constexpr (NPROD == 3)
                alf = *(const short8*)&As_lo[cb + (wr + mi * 16 + l15) * 32 + quad * 8];
            #pragma unroll
            for (int ni = 0; ni < 4; ++ni) {
                acc[mi][ni] = __builtin_amdgcn_mfma_f32_16x16x32_bf16(ahf, bhf[ni], acc[mi][ni], 0, 0, 0);
                if constexpr (NPROD == 3) {
                    acc[mi][ni] = __builtin_amdgcn_mfma_f32_16x16x32_bf16(ahf, blf[ni], acc[mi][ni], 0, 0, 0);
                    acc[mi][ni] = __builtin_amdgcn_mfma_f32_16x16x32_bf16(alf, bhf[ni], acc[mi][ni], 0, 0, 0);
                }
            }
        }
        // bare barrier (no vmcnt drain): all cb ds_reads were consumed by the
        // MFMAs above; cb is now free for the next iteration's STAGE.
        __builtin_amdgcn_s_barrier();
    }

    if constexpr (OUTMODE == 0) {
        #pragma unroll
        for (int mi = 0; mi < 4; ++mi)
            #pragma unroll
            for (int ni = 0; ni < 4; ++ni) {
                int r = row0 + wr + mi * 16 + quad * 4;
                int c = col0 + wc + ni * 16 + l15;
                #pragma unroll
                for (int reg = 0; reg < 4; ++reg)
                    Cf[(size_t)(r + reg) * En + c] = acc[mi][ni][reg];
            }
    } else if constexpr (OUTMODE == 1) {
        // LDS transpose -> coalesced V^T stores
        #pragma unroll
        for (int mi = 0; mi < 4; ++mi)
            #pragma unroll
            for (int ni = 0; ni < 4; ++ni) {
                int dl = wc + ni * 16 + l15;            // local col (d)
                int sl = wr + mi * 16 + quad * 4;       // local row (s)
                #pragma unroll
                for (int reg = 0; reg < 4; ++reg)
                    Ts[dl * 136 + sl + reg] = f2bf(acc[mi][ni][reg]);
            }
        __syncthreads();
        int dl = tid >> 1, s0 = (tid & 1) * 64;
        int b = row0 >> 11, h = col0 >> 7;
        size_t gbase = ((size_t)(b * Hn + h) * HDn + dl) * Sn + (row0 & (Sn - 1)) + s0;
        #pragma unroll
        for (int k = 0; k < 8; ++k) {
            short8 vv = *(const short8*)&Ts[dl * 136 + s0 + k * 8];
            *(short8*)&Cbt[gbase + k * 8] = vv;
        }
    } else {
        int* dst = (col0 >= 2048) ? Kpk : Qpk;
        const int cb = col0 & 2047;
        #pragma unroll
        for (int mi = 0; mi < 4; ++mi)
            #pragma unroll
            for (int ni = 0; ni < 4; ++ni) {
                int r = row0 + wr + mi * 16 + quad * 4;
                int c = cb + wc + ni * 16 + l15;
                #pragma unroll
                for (int reg = 0; reg < 4; ++reg) {
                    float v = acc[mi][ni][reg];
                    short hh = f2bf(v);
                    short ll = f2bf(v - bf2f(hh));
                    dst[(size_t)(r + reg) * 2048 + c] =
                        ((int)(unsigned short)hh << 16) | (unsigned short)ll;
                }
            }
    }
}

// ---- RoPE on packed (hi<<16|lo) int32 -> split bf16 planes ----
static __global__ void rope_pk_kernel(const int* __restrict__ Pre,
        short* __restrict__ Yh, short* __restrict__ Yl,
        const float* __restrict__ sinT, const float* __restrict__ cosT) {
    int p = blockIdx.x * 256 + threadIdx.x;       // < 2^21 ; 4 elements/thread
    int u = p & 511;
    int t = (p >> 9) & (Sn - 1);
    int b = p >> 20;
    int tsrc; float sgn;
    if (t < Sn / 2) { tsrc = 2 * t + 1; sgn = -1.f; }
    else            { tsrc = 2 * (t - Sn / 2); sgn = 1.f; }
    int f0 = (2 * u) & 63, f1 = (2 * u + 1) & 63;
    float sv0 = sinT[(t << 6) + f0], cv0 = cosT[(t << 6) + f0];
    float sv1 = sinT[(t << 6) + f1], cv1 = cosT[(t << 6) + f1];
    size_t rt = ((size_t)(b * Sn + t)) * 512 + u;     // int4 units
    size_t rs = ((size_t)(b * Sn + tsrc)) * 512 + u;
    int4 xt = ((const int4*)Pre)[rt];
    int4 xs = ((const int4*)Pre)[rs];
    auto up = [](int v) -> float {
        return bf2f((short)(v >> 16)) + bf2f((short)(v & 0xffff));
    };
    float x0 = up(xt.x), x1 = up(xt.y), x2 = up(xt.z), x3 = up(xt.w);
    float s0 = up(xs.x), s1 = up(xs.y), s2 = up(xs.z), s3 = up(xs.w);
    float y0 = x0 * cv0 + sgn * s0 * sv0;
    float y1 = x1 * cv0 + sgn * s1 * sv0;
    float y2 = x2 * cv1 + sgn * s2 * sv1;
    float y3 = x3 * cv1 + sgn * s3 * sv1;
    short4 hi, lo;
    hi.x = f2bf(y0); lo.x = f2bf(y0 - bf2f(hi.x));
    hi.y = f2bf(y1); lo.y = f2bf(y1 - bf2f(hi.y));
    hi.z = f2bf(y2); lo.z = f2bf(y2 - bf2f(hi.z));
    hi.w = f2bf(y3); lo.w = f2bf(y3 - bf2f(hi.w));
    size_t o = ((size_t)(b * Sn + t)) * En + 4 * u;
    *(short4*)&Yh[o] = hi;
    *(short4*)&Yl[o] = lo;
}

// ---- MFMA flash attention v9 ----
// 512 threads (8 waves), 128 q-rows/block, 64-key tiles; flash5 per-tile
// compute (identical numerics) + K/V LDS DOUBLE-BUFFER with stage-early /
// drain-late: stage tile j+1 into buf^1 at top of iter, compute tile j from
// buf, ONE __syncthreads per tile at the END. (Counted vmcnt NOT applied
// here: the loop's 16 interleaved mask loads make the count compiler-
// dependent, and flash9's long compute phase already covers the drain.)
// LDS (shorts): buf0 [0,24576): K-hi/K-lo/V each 8192
//               buf1 [24576,49152): same layout
//               P    [49152,59392): 8 waves x 1280
// Q staged transiently in [0,32768) before buffers are first used.
// 118784 B -> 1 block/CU (8 waves).
static __global__ __launch_bounds__(512, 2) void flash9_kernel(
        const short* __restrict__ Qhi, const short* __restrict__ Qlo,
        const short* __restrict__ Khi, const short* __restrict__ Klo,
        const short* __restrict__ Vt, const short* __restrict__ maskB,
        short* __restrict__ AO) {
    __shared__ short lds0[59392];

    const int tid = threadIdx.x;
    const int w = tid >> 6, l = tid & 63;
    const int quad = l >> 4, l15 = l & 15;
    const int n = blockIdx.x;
    const int bh = (n & 7) * 4 + ((n >> 3) & 3);   // heads grouped per XCD
    const int qt = n >> 5;                          // 32 consecutive blocks share mask rows
    const int b = bh >> 4, h = bh & 15;
    const int r0 = qt * 128;
    const size_t qkbase = (size_t)b * Sn * En + (size_t)h * HDn;
    const int psb = 49152 + w * 1280;

    // ---- stage Q (transient, overlaps buffer region) ----
    #pragma unroll
    for (int c = 0; c < 4; ++c) {
        int off = tid * 16 + c * 8192;
        int row = off >> 8;
        int gp = (off >> 4) & 15;
        int gl = gp ^ (row & 7);
        size_t gidx = qkbase + (size_t)(r0 + row) * En + gl * 8;
        gl_lds16(Qhi + gidx, &lds0[off / 2]);
        gl_lds16(Qlo + gidx, &lds0[16384 + off / 2]);
    }
    __syncthreads();
    short8 qh[4], ql[4];
    {
        int row = 16 * w + l15;
        #pragma unroll
        for (int kc = 0; kc < 4; ++kc) {
            int gp = (kc * 4 + quad) ^ (row & 7);
            qh[kc] = *(const short8*)&lds0[row * 128 + gp * 8];
            ql[kc] = *(const short8*)&lds0[16384 + row * 128 + gp * 8];
        }
    }
    __syncthreads();   // all waves done reading Q before buffers are written

    // ---- staging helper: K hi/lo + V for key-tile jj into buffer at bbase ----
    auto STAGE = [&](int bbase, int jj) {
        #pragma unroll
        for (int c = 0; c < 2; ++c) {          // K hi/lo (64 rows x 256 B)
            int off = tid * 16 + c * 8192;     // [0,16384) bytes
            int row = off >> 8;                // 0..63
            int gp = (off >> 4) & 15;
            int gl = gp ^ (row & 7);
            size_t gidx = qkbase + (size_t)(jj + row) * En + gl * 8;
            gl_lds16(Khi + gidx, &lds0[bbase + off / 2]);
            gl_lds16(Klo + gidx, &lds0[bbase + 8192 + off / 2]);
        }
        #pragma unroll
        for (int c = 0; c < 2; ++c) {          // V (128 d-rows x 128 B)
            int off = tid * 16 + c * 8192;     // [0,16384) bytes
            int vrow = off >> 7;               // 0..127
            int vgp = (off >> 4) & 7;
            int vgl = vgp ^ (vrow & 7);
            size_t vidx = ((size_t)bh * HDn + vrow) * Sn + jj + vgl * 8;
            gl_lds16(Vt + vidx, &lds0[bbase + 16384 + off / 2]);
        }
    };

    STAGE(0, 0);          // tile 0 -> buf0
    __syncthreads();      // only prologue drain that exposes latency

    f32x4 O[8];
    #pragma unroll
    for (int di = 0; di < 8; ++di) O[di] = f32x4{0.f, 0.f, 0.f, 0.f};
    float m_prev[4] = {-INFINITY, -INFINITY, -INFINITY, -INFINITY};
    float l_run[4] = {0.f, 0.f, 0.f, 0.f};
    const int qrow_base = r0 + 16 * w + quad * 4;

    for (int j0 = 0; j0 < Sn; j0 += 64) {
        const int bb = ((j0 >> 6) & 1) * 24576;   // current buffer base
        const int nb = bb ^ 24576;                // next buffer base

        float mv[4][4];                        // bf16 mask prefetch (pre-scaled)
        #pragma unroll
        for (int ni = 0; ni < 4; ++ni)
            #pragma unroll
            for (int reg = 0; reg < 4; ++reg)
                mv[ni][reg] = bf2f(maskB[(size_t)(qrow_base + reg) * Sn + j0 + ni * 16 + l15]);

        if (j0 + 64 < Sn) STAGE(nb, j0 + 64);  // prefetch next tile (drained at end-of-iter barrier)

        // ---- QK^T (3 split products) from buf[bb] ----
        f32x4 p[4];
        #pragma unroll
        for (int ni = 0; ni < 4; ++ni) p[ni] = f32x4{0.f, 0.f, 0.f, 0.f};
        #pragma unroll
        for (int ni = 0; ni < 4; ++ni) {
            int col = ni * 16 + l15;
            #pragma unroll
            for (int kc = 0; kc < 4; ++kc) {
                int gp = (kc * 4 + quad) ^ (col & 7);
                short8 kh = *(const short8*)&lds0[bb + col * 128 + gp * 8];
                short8 kl = *(const short8*)&lds0[bb + 8192 + col * 128 + gp * 8];
                p[ni] = __builtin_amdgcn_mfma_f32_16x16x32_bf16(qh[kc], kh, p[ni], 0, 0, 0);
                p[ni] = __builtin_amdgcn_mfma_f32_16x16x32_bf16(qh[kc], kl, p[ni], 0, 0, 0);
                p[ni] = __builtin_amdgcn_mfma_f32_16x16x32_bf16(ql[kc], kh, p[ni], 0, 0, 0);
            }
        }

        // ---- softmax in base 2, DPP reductions (flash5 math, unchanged) ----
        float rm[4] = {-INFINITY, -INFINITY, -INFINITY, -INFINITY};
        #pragma unroll
        for (int ni = 0; ni < 4; ++ni)
            #pragma unroll
            for (int reg = 0; reg < 4; ++reg) {
                float v = fmaf(p[ni][reg], NORMS2, mv[ni][reg]);
                p[ni][reg] = v;
                rm[reg] = fmaxf(rm[reg], v);
            }
        #pragma unroll
        for (int reg = 0; reg < 4; ++reg) rm[reg] = redmax16(rm[reg]);
        float al[4], mn[4], rs[4];
        #pragma unroll
        for (int reg = 0; reg < 4; ++reg) {
            mn[reg] = fmaxf(m_prev[reg], rm[reg]);
            al[reg] = EXP2(m_prev[reg] - mn[reg]);
            rs[reg] = 0.f;
        }
        #pragma unroll
        for (int ni = 0; ni < 4; ++ni)
            #pragma unroll
            for (int reg = 0; reg < 4; ++reg) {
                float pe = EXP2(p[ni][reg] - mn[reg]);
                rs[reg] += pe;
                lds0[psb + (quad * 4 + reg) * 80 + ((ni ^ quad) << 4) + l15] = f2bf(pe);
            }
        #pragma unroll
        for (int reg = 0; reg < 4; ++reg) rs[reg] = redsum16(rs[reg]);
        #pragma unroll
        for (int reg = 0; reg < 4; ++reg) {
            l_run[reg] = l_run[reg] * al[reg] + rs[reg];
            m_prev[reg] = mn[reg];
        }
        #pragma unroll
        for (int di = 0; di < 8; ++di)
            #pragma unroll
            for (int reg = 0; reg < 4; ++reg)
                O[di][reg] *= al[reg];

        short8 pa[2];
        #pragma unroll
        for (int kc2 = 0; kc2 < 2; ++kc2) {
            int g = kc2 * 2 + (quad >> 1);
            int gs = g ^ (l15 >> 2);
            pa[kc2] = *(const short8*)&lds0[psb + l15 * 80 + (gs << 4) + (quad & 1) * 8];
        }

        // ---- PV from buf[bb] ----
        #pragma unroll
        for (int di = 0; di < 8; ++di) {
            int d = di * 16 + l15;
            #pragma unroll
            for (int kc2 = 0; kc2 < 2; ++kc2) {
                int gp = (kc2 * 4 + quad) ^ (d & 7);
                short8 vb = *(const short8*)&lds0[bb + 16384 + d * 64 + gp * 8];
                O[di] = __builtin_amdgcn_mfma_f32_16x16x32_bf16(pa[kc2], vb, O[di], 0, 0, 0);
            }
        }

        // ONE barrier per tile: prev-iter prefetch now visible to all waves,
        // and buf[bb] is free to be overwritten next iteration.
        __syncthreads();
    }

    float inv[4];
    #pragma unroll
    for (int reg = 0; reg < 4; ++reg) inv[reg] = 1.0f / l_run[reg];
    #pragma unroll
    for (int di = 0; di < 8; ++di)
        #pragma unroll
        for (int reg = 0; reg < 4; ++reg) {
            size_t idx = ((size_t)b * Sn + qrow_base + reg) * En + h * HDn + di * 16 + l15;
            AO[idx] = f2bf(O[di][reg] * inv[reg]);
        }
}

extern "C" void kernel_launch(void* const* d_in, const int* in_sizes, int n_in,
                              void* d_out, int out_size, void* d_ws, size_t ws_size,
                              hipStream_t stream) {
    const float* inputs = (const float*)d_in[0];
    const float* mask   = (const float*)d_in[1];
    const float* wq     = (const float*)d_in[2];
    const float* wk     = (const float*)d_in[3];
    const float* wv     = (const float*)d_in[4];
    const float* wo     = (const float*)d_in[5];
    float* out = (float*)d_out;
    (void)in_sizes; (void)n_in; (void)out_size; (void)ws_size;

    char* W8 = (char*)d_ws;
    float* sinT  = (float*)(W8 + 0);
    float* cosT  = (float*)(W8 + 524288);
    short* Xhi   = (short*)(W8 + 1048576);
    short* Xlo   = (short*)(W8 + 17825792);
    short* maskB = (short*)(W8 + 34603008);
    short* WqkTh = (short*)(W8 + 42991616);
    short* WqkTl = (short*)(W8 + 59768832);
    short* WvT   = (short*)(W8 + 76546048);
    short* WoT   = (short*)(W8 + 84934656);
    int*   Qpk   = (int*)(W8 + 93323264);
    int*   Kpk   = (int*)(W8 + 126877696);
    // aliases (lifetimes disjoint; ordering enforced by dispatch sequence):
    short* Qhi = WqkTh;                        // rope-Q out over W-qk (dead after QK-GEMM)
    short* Qlo = WqkTl;
    short* Khi = (short*)(W8 + 93323264);      // rope-K out over Qpk (dead after rope-Q)
    short* Klo = (short*)(W8 + 110100480);
    short* Vt  = (short*)(W8 + 126877696);     // V^T over Kpk (dead after rope-K)
    short* AO  = Xhi;                          // flash out over X-hi (dead after V-GEMM)

    rope_table_kernel<<<512, 256, 0, stream>>>(sinT, cosT);
    split_x_kernel<<<8192, 256, 0, stream>>>(inputs, Xhi, Xlo);
    maskconv_kernel<<<4096, 256, 0, stream>>>(mask, maskB);
    wtrans4_kernel<<<dim3(64, 64, 4), 256, 0, stream>>>(wq, wk, wv, wo,
                                                        WqkTh, WqkTl, WvT, WoT);

    gemm_kernel<3, 3><<<dim3(32, 32), 256, 0, stream>>>(
        Xhi, Xlo, WqkTh, WqkTl, nullptr, nullptr, Qpk, Kpk);
    rope_pk_kernel<<<8192, 256, 0, stream>>>(Qpk, Qhi, Qlo, sinT, cosT);
    rope_pk_kernel<<<8192, 256, 0, stream>>>(Kpk, Khi, Klo, sinT, cosT);
    gemm_kernel<1, 1><<<dim3(16, 32), 256, 0, stream>>>(
        Xhi, nullptr, WvT, nullptr, nullptr, Vt, nullptr, nullptr);

    flash9_kernel<<<512, 512, 0, stream>>>(Qhi, Qlo, Khi, Klo, Vt, maskB, AO);

    gemm_kernel<1, 0><<<dim3(16, 32), 256, 0, stream>>>(
        AO, nullptr, WoT, nullptr, out, nullptr, nullptr, nullptr);
}

// Round 7
// 648.240 us; speedup vs baseline: 1.1576x; 1.0219x over previous
//
#include <hip/hip_runtime.h>
#include <hip/hip_bf16.h>
#include <cmath>

#define Bn 2
#define Sn 2048
#define En 2048
#define Hn 16
#define HDn 128
#define Mn (Bn*Sn)
#define NORMS2 92.33248261689366f   /* 64 * log2(e) : softmax done in base 2 */

typedef __attribute__((ext_vector_type(8))) short short8;
typedef __attribute__((ext_vector_type(4))) float f32x4;

__device__ __forceinline__ short f2bf(float x) {
    __hip_bfloat16 h = __float2bfloat16(x);
    return *reinterpret_cast<short*>(&h);
}
__device__ __forceinline__ float bf2f(short s) {
    __hip_bfloat16 h = *reinterpret_cast<__hip_bfloat16*>(&s);
    return __bfloat162float(h);
}
__device__ __forceinline__ void gl_lds16(const void* g, void* l) {
    __builtin_amdgcn_global_load_lds(
        (const __attribute__((address_space(1))) unsigned int*)g,
        (__attribute__((address_space(3))) unsigned int*)l, 16, 0, 0);
}

#if __has_builtin(__builtin_amdgcn_exp2f)
#define EXP2(x) __builtin_amdgcn_exp2f(x)
#else
#define EXP2(x) exp2f(x)
#endif

template<int CTRL>
__device__ __forceinline__ float dppf(float x) {
    int r = __builtin_amdgcn_update_dpp(0, __builtin_bit_cast(int, x), CTRL, 0xf, 0xf, true);
    return __builtin_bit_cast(float, r);
}
__device__ __forceinline__ float redmax16(float x) {
    x = fmaxf(x, dppf<0xB1>(x));   // quad_perm xor1
    x = fmaxf(x, dppf<0x4E>(x));   // quad_perm xor2
    x = fmaxf(x, dppf<0x141>(x));  // row_half_mirror xor7
    x = fmaxf(x, dppf<0x140>(x));  // row_mirror xor15
    return x;
}
__device__ __forceinline__ float redsum16(float x) {
    x += dppf<0xB1>(x);
    x += dppf<0x4E>(x);
    x += dppf<0x141>(x);
    x += dppf<0x140>(x);
    return x;
}

// ---- sin/cos tables in fp64 ----
static __global__ void rope_table_kernel(float* __restrict__ sinT, float* __restrict__ cosT) {
    int i = blockIdx.x * 256 + threadIdx.x;
    int t = i >> 6, f = i & 63;
    double inv = pow(10000.0, -(double)(2 * f) / (double)HDn);
    double ang = (double)t * inv;
    sinT[i] = (float)sin(ang);
    cosT[i] = (float)cos(ang);
}

// ---- split fp32 -> bf16 hi/lo ----
static __global__ void split_x_kernel(const float* __restrict__ X,
                                      short* __restrict__ Xhi, short* __restrict__ Xlo) {
    int i = (blockIdx.x * 256 + threadIdx.x) * 4;
    float4 x = *(const float4*)&X[i];
    short4 hi, lo;
    hi.x = f2bf(x.x); lo.x = f2bf(x.x - bf2f(hi.x));
    hi.y = f2bf(x.y); lo.y = f2bf(x.y - bf2f(hi.y));
    hi.z = f2bf(x.z); lo.z = f2bf(x.z - bf2f(hi.z));
    hi.w = f2bf(x.w); lo.w = f2bf(x.w - bf2f(hi.w));
    *(short4*)&Xhi[i] = hi;
    *(short4*)&Xlo[i] = lo;
}

// ---- mask fp32 -> bf16, pre-scaled by NORMS2 (exact for zero mask) ----
static __global__ void maskconv_kernel(const float* __restrict__ M, short* __restrict__ MB) {
    int i = (blockIdx.x * 256 + threadIdx.x) * 4;
    float4 m = *(const float4*)&M[i];
    short4 o;
    o.x = f2bf(m.x * NORMS2); o.y = f2bf(m.y * NORMS2);
    o.z = f2bf(m.z * NORMS2); o.w = f2bf(m.w * NORMS2);
    *(short4*)&MB[i] = o;
}

// ---- transpose all 4 weights in one dispatch (z selects) ----
static __global__ __launch_bounds__(256) void wtrans4_kernel(
        const float* __restrict__ Wq, const float* __restrict__ Wk,
        const float* __restrict__ Wv, const float* __restrict__ Wo,
        short* __restrict__ QKh, short* __restrict__ QKl,
        short* __restrict__ VT, short* __restrict__ OT) {
    __shared__ float tile[32][33];
    const int z = blockIdx.z;
    const float* W = (z == 0) ? Wq : (z == 1) ? Wk : (z == 2) ? Wv : Wo;
    short* Th = (z <= 1) ? QKh : (z == 2) ? VT : OT;
    const int rowoff = (z == 1) ? 2048 : 0;
    const bool split = (z <= 1);
    int tx = threadIdx.x & 31, ty = threadIdx.x >> 5;
    int k0 = blockIdx.y * 32, n0 = blockIdx.x * 32;
    #pragma unroll
    for (int i = 0; i < 4; ++i)
        tile[ty + i * 8][tx] = W[(size_t)(k0 + ty + i * 8) * En + n0 + tx];
    __syncthreads();
    #pragma unroll
    for (int i = 0; i < 4; ++i) {
        float v = tile[tx][ty + i * 8];
        size_t idx = (size_t)(rowoff + n0 + ty + i * 8) * En + k0 + tx;
        short hv = f2bf(v);
        Th[idx] = hv;
        if (split) QKl[idx] = f2bf(v - bf2f(hv));
    }
}

// ---- MFMA GEMM: C[M][N] = A[M][K] * BT[N][K]^T, 128x128 tile, BK=32 ----
// v4: dbuf + counted vmcnt (R5) + T2 LDS XOR-SWIZZLE. The [128][32]-short
// tile has 64B rows -> fragment reads put 16 lanes on 2 bank-groups (8-way
// conflict, 1.68e7 cyc). Fix per rule #21 (gl_lds writes linearly): LDS dest
// stays LINEAR; the GLOBAL source column is pre-swizzled per staging thread
// (slot ^= (row>>1)&3, 16B slots), and fragment reads apply the same XOR:
// slot = quad ^ ((row>>1)&3). stored(row,s)=global(row,s^swz); read at
// s=quad^swz -> global(row,quad): bit-identical operands, numerics unchanged.
// New pattern: each (row-parity, slot) pair = 2 lanes -> 2-way = free (m136).
// NPROD=3: split products (hi*hi + hi*lo + lo*hi)
// OUTMODE=0: fp32 row-major -> Cf
// OUTMODE=1: bf16 V^T [(b,h,d)][s] via LDS transpose (coalesced) -> Cbt
// OUTMODE=3: packed (hi<<16|lo) int32 row-major, cols<2048 -> Qpk else Kpk
template<int NPROD, int OUTMODE>
static __global__ __launch_bounds__(256) void gemm_kernel(
        const short* __restrict__ Ahi, const short* __restrict__ Alo,
        const short* __restrict__ Bhi, const short* __restrict__ Blo,
        float* __restrict__ Cf, short* __restrict__ Cbt,
        int* __restrict__ Qpk, int* __restrict__ Kpk) {
    __shared__ short As_hi[2 * 128 * 32];
    __shared__ short Bs_hi[2 * 128 * 32];
    __shared__ short As_lo[NPROD == 3 ? 2 * 128 * 32 : 8];
    __shared__ short Bs_lo[NPROD == 3 ? 2 * 128 * 32 : 8];
    __shared__ short Ts[OUTMODE == 1 ? 128 * 136 : 8];

    const int tid = threadIdx.x;
    const int w = tid >> 6, l = tid & 63;
    const int quad = l >> 4, l15 = l & 15;
    const int wr = (w >> 1) * 64, wc = (w & 1) * 64;
    const int row0 = blockIdx.y * 128, col0 = blockIdx.x * 128;

    const int off0 = tid * 16;
    const int r_a = off0 >> 6;                  // staging row 0..63 (and +64)
    // T2 pre-swizzled source column: slot ^ ((row>>1)&3); invariant under
    // row+64 so one value serves both gl_lds16 calls of this thread.
    const int slot = (off0 >> 4) & 3;
    const int kb = (slot ^ ((r_a >> 1) & 3)) * 8;   // shorts

    // stage one 128x32 K-tile (all planes) into buffer at short-offset bs
    // NPROD==3: 8 gl_lds per call; NPROD==1: 4 gl_lds per call.
    auto STAGE = [&](int bs, int kk) {
        const short* ap = Ahi + (size_t)(row0 + r_a) * En + kk + kb;
        const short* bp = Bhi + (size_t)(col0 + r_a) * En + kk + kb;
        gl_lds16(ap,           &As_hi[bs + off0 / 2]);
        gl_lds16(ap + 64 * En, &As_hi[bs + (off0 + 4096) / 2]);
        gl_lds16(bp,           &Bs_hi[bs + off0 / 2]);
        gl_lds16(bp + 64 * En, &Bs_hi[bs + (off0 + 4096) / 2]);
        if constexpr (NPROD == 3) {
            const short* ap2 = Alo + (size_t)(row0 + r_a) * En + kk + kb;
            const short* bp2 = Blo + (size_t)(col0 + r_a) * En + kk + kb;
            gl_lds16(ap2,           &As_lo[bs + off0 / 2]);
            gl_lds16(ap2 + 64 * En, &As_lo[bs + (off0 + 4096) / 2]);
            gl_lds16(bp2,           &Bs_lo[bs + off0 / 2]);
            gl_lds16(bp2 + 64 * En, &Bs_lo[bs + (off0 + 4096) / 2]);
        }
    };

    f32x4 acc[4][4];
    #pragma unroll
    for (int i = 0; i < 4; ++i)
        #pragma unroll
        for (int j = 0; j < 4; ++j) acc[i][j] = f32x4{0.f, 0.f, 0.f, 0.f};

    STAGE(0, 0);
    __syncthreads();   // prologue: full drain once (tile 0 visible)

    for (int k0 = 0; k0 < En; k0 += 32) {
        const int cb = ((k0 >> 5) & 1) * 4096;   // current buffer (shorts)
        const int nb = cb ^ 4096;                // next buffer
        if (k0 + 32 < En) {
            STAGE(nb, k0 + 32);                  // prefetch stays in flight
            // wait ONLY the previous iter's loads (the cb about to be read):
            asm volatile("s_waitcnt vmcnt(%0)" :: "i"(NPROD == 3 ? 8 : 4) : "memory");
        } else {
            asm volatile("s_waitcnt vmcnt(0)" ::: "memory");  // last tile: drain
        }
        __builtin_amdgcn_sched_barrier(0);       // rule #18: pin order
        __builtin_amdgcn_s_barrier();            // all waves' cb loads complete

        short8 bhf[4], blf[4];
        #pragma unroll
        for (int ni = 0; ni < 4; ++ni) {
            int br = wc + ni * 16 + l15;
            int bsw = (quad ^ ((br >> 1) & 3)) * 8;
            bhf[ni] = *(const short8*)&Bs_hi[cb + br * 32 + bsw];
            if constexpr (NPROD == 3)
                blf[ni] = *(const short8*)&Bs_lo[cb + br * 32 + bsw];
        }
        #pragma unroll
        for (int mi = 0; mi < 4; ++mi) {
            int ar = wr + mi * 16 + l15;
            int asw = (quad ^ ((ar >> 1) & 3)) * 8;
            short8 ahf = *(const short8*)&As_hi[cb + ar * 32 + asw];
            short8 alf;
            if constexpr (NPROD == 3)
                alf = *(const short8*)&As_lo[cb + ar * 32 + asw];
            #pragma unroll
            for (int ni = 0; ni < 4; ++ni) {
                acc[mi][ni] = __builtin_amdgcn_mfma_f32_16x16x32_bf16(ahf, bhf[ni], acc[mi][ni], 0, 0, 0);
                if constexpr (NPROD == 3) {
                    acc[mi][ni] = __builtin_amdgcn_mfma_f32_16x16x32_bf16(ahf, blf[ni], acc[mi][ni], 0, 0, 0);
                    acc[mi][ni] = __builtin_amdgcn_mfma_f32_16x16x32_bf16(alf, bhf[ni], acc[mi][ni], 0, 0, 0);
                }
            }
        }
        // bare barrier (no vmcnt drain): all cb ds_reads were consumed by the
        // MFMAs above; cb is now free for the next iteration's STAGE.
        __builtin_amdgcn_s_barrier();
    }

    if constexpr (OUTMODE == 0) {
        #pragma unroll
        for (int mi = 0; mi < 4; ++mi)
            #pragma unroll
            for (int ni = 0; ni < 4; ++ni) {
                int r = row0 + wr + mi * 16 + quad * 4;
                int c = col0 + wc + ni * 16 + l15;
                #pragma unroll
                for (int reg = 0; reg < 4; ++reg)
                    Cf[(size_t)(r + reg) * En + c] = acc[mi][ni][reg];
            }
    } else if constexpr (OUTMODE == 1) {
        // LDS transpose -> coalesced V^T stores
        #pragma unroll
        for (int mi = 0; mi < 4; ++mi)
            #pragma unroll
            for (int ni = 0; ni < 4; ++ni) {
                int dl = wc + ni * 16 + l15;            // local col (d)
                int sl = wr + mi * 16 + quad * 4;       // local row (s)
                #pragma unroll
                for (int reg = 0; reg < 4; ++reg)
                    Ts[dl * 136 + sl + reg] = f2bf(acc[mi][ni][reg]);
            }
        __syncthreads();
        int dl = tid >> 1, s0 = (tid & 1) * 64;
        int b = row0 >> 11, h = col0 >> 7;
        size_t gbase = ((size_t)(b * Hn + h) * HDn + dl) * Sn + (row0 & (Sn - 1)) + s0;
        #pragma unroll
        for (int k = 0; k < 8; ++k) {
            short8 vv = *(const short8*)&Ts[dl * 136 + s0 + k * 8];
            *(short8*)&Cbt[gbase + k * 8] = vv;
        }
    } else {
        int* dst = (col0 >= 2048) ? Kpk : Qpk;
        const int cb = col0 & 2047;
        #pragma unroll
        for (int mi = 0; mi < 4; ++mi)
            #pragma unroll
            for (int ni = 0; ni < 4; ++ni) {
                int r = row0 + wr + mi * 16 + quad * 4;
                int c = cb + wc + ni * 16 + l15;
                #pragma unroll
                for (int reg = 0; reg < 4; ++reg) {
                    float v = acc[mi][ni][reg];
                    short hh = f2bf(v);
                    short ll = f2bf(v - bf2f(hh));
                    dst[(size_t)(r + reg) * 2048 + c] =
                        ((int)(unsigned short)hh << 16) | (unsigned short)ll;
                }
            }
    }
}

// ---- RoPE on packed (hi<<16|lo) int32 -> split bf16 planes ----
static __global__ void rope_pk_kernel(const int* __restrict__ Pre,
        short* __restrict__ Yh, short* __restrict__ Yl,
        const float* __restrict__ sinT, const float* __restrict__ cosT) {
    int p = blockIdx.x * 256 + threadIdx.x;       // < 2^21 ; 4 elements/thread
    int u = p & 511;
    int t = (p >> 9) & (Sn - 1);
    int b = p >> 20;
    int tsrc; float sgn;
    if (t < Sn / 2) { tsrc = 2 * t + 1; sgn = -1.f; }
    else            { tsrc = 2 * (t - Sn / 2); sgn = 1.f; }
    int f0 = (2 * u) & 63, f1 = (2 * u + 1) & 63;
    float sv0 = sinT[(t << 6) + f0], cv0 = cosT[(t << 6) + f0];
    float sv1 = sinT[(t << 6) + f1], cv1 = cosT[(t << 6) + f1];
    size_t rt = ((size_t)(b * Sn + t)) * 512 + u;     // int4 units
    size_t rs = ((size_t)(b * Sn + tsrc)) * 512 + u;
    int4 xt = ((const int4*)Pre)[rt];
    int4 xs = ((const int4*)Pre)[rs];
    auto up = [](int v) -> float {
        return bf2f((short)(v >> 16)) + bf2f((short)(v & 0xffff));
    };
    float x0 = up(xt.x), x1 = up(xt.y), x2 = up(xt.z), x3 = up(xt.w);
    float s0 = up(xs.x), s1 = up(xs.y), s2 = up(xs.z), s3 = up(xs.w);
    float y0 = x0 * cv0 + sgn * s0 * sv0;
    float y1 = x1 * cv0 + sgn * s1 * sv0;
    float y2 = x2 * cv1 + sgn * s2 * sv1;
    float y3 = x3 * cv1 + sgn * s3 * sv1;
    short4 hi, lo;
    hi.x = f2bf(y0); lo.x = f2bf(y0 - bf2f(hi.x));
    hi.y = f2bf(y1); lo.y = f2bf(y1 - bf2f(hi.y));
    hi.z = f2bf(y2); lo.z = f2bf(y2 - bf2f(hi.z));
    hi.w = f2bf(y3); lo.w = f2bf(y3 - bf2f(hi.w));
    size_t o = ((size_t)(b * Sn + t)) * En + 4 * u;
    *(short4*)&Yh[o] = hi;
    *(short4*)&Yl[o] = lo;
}

// ---- MFMA flash attention v9 ----
// 512 threads (8 waves), 128 q-rows/block, 64-key tiles; flash5 per-tile
// compute (identical numerics) + K/V LDS DOUBLE-BUFFER with stage-early /
// drain-late: stage tile j+1 into buf^1 at top of iter, compute tile j from
// buf, ONE __syncthreads per tile at the END.
// LDS (shorts): buf0 [0,24576): K-hi/K-lo/V each 8192
//               buf1 [24576,49152): same layout
//               P    [49152,59392): 8 waves x 1280
// Q staged transiently in [0,32768) before buffers are first used.
// 118784 B -> 1 block/CU (8 waves).
static __global__ __launch_bounds__(512, 2) void flash9_kernel(
        const short* __restrict__ Qhi, const short* __restrict__ Qlo,
        const short* __restrict__ Khi, const short* __restrict__ Klo,
        const short* __restrict__ Vt, const short* __restrict__ maskB,
        short* __restrict__ AO) {
    __shared__ short lds0[59392];

    const int tid = threadIdx.x;
    const int w = tid >> 6, l = tid & 63;
    const int quad = l >> 4, l15 = l & 15;
    const int n = blockIdx.x;
    const int bh = (n & 7) * 4 + ((n >> 3) & 3);   // heads grouped per XCD
    const int qt = n >> 5;                          // 32 consecutive blocks share mask rows
    const int b = bh >> 4, h = bh & 15;
    const int r0 = qt * 128;
    const size_t qkbase = (size_t)b * Sn * En + (size_t)h * HDn;
    const int psb = 49152 + w * 1280;

    // ---- stage Q (transient, overlaps buffer region) ----
    #pragma unroll
    for (int c = 0; c < 4; ++c) {
        int off = tid * 16 + c * 8192;
        int row = off >> 8;
        int gp = (off >> 4) & 15;
        int gl = gp ^ (row & 7);
        size_t gidx = qkbase + (size_t)(r0 + row) * En + gl * 8;
        gl_lds16(Qhi + gidx, &lds0[off / 2]);
        gl_lds16(Qlo + gidx, &lds0[16384 + off / 2]);
    }
    __syncthreads();
    short8 qh[4], ql[4];
    {
        int row = 16 * w + l15;
        #pragma unroll
        for (int kc = 0; kc < 4; ++kc) {
            int gp = (kc * 4 + quad) ^ (row & 7);
            qh[kc] = *(const short8*)&lds0[row * 128 + gp * 8];
            ql[kc] = *(const short8*)&lds0[16384 + row * 128 + gp * 8];
        }
    }
    __syncthreads();   // all waves done reading Q before buffers are written

    // ---- staging helper: K hi/lo + V for key-tile jj into buffer at bbase ----
    auto STAGE = [&](int bbase, int jj) {
        #pragma unroll
        for (int c = 0; c < 2; ++c) {          // K hi/lo (64 rows x 256 B)
            int off = tid * 16 + c * 8192;     // [0,16384) bytes
            int row = off >> 8;                // 0..63
            int gp = (off >> 4) & 15;
            int gl = gp ^ (row & 7);
            size_t gidx = qkbase + (size_t)(jj + row) * En + gl * 8;
            gl_lds16(Khi + gidx, &lds0[bbase + off / 2]);
            gl_lds16(Klo + gidx, &lds0[bbase + 8192 + off / 2]);
        }
        #pragma unroll
        for (int c = 0; c < 2; ++c) {          // V (128 d-rows x 128 B)
            int off = tid * 16 + c * 8192;     // [0,16384) bytes
            int vrow = off >> 7;               // 0..127
            int vgp = (off >> 4) & 7;
            int vgl = vgp ^ (vrow & 7);
            size_t vidx = ((size_t)bh * HDn + vrow) * Sn + jj + vgl * 8;
            gl_lds16(Vt + vidx, &lds0[bbase + 16384 + off / 2]);
        }
    };

    STAGE(0, 0);          // tile 0 -> buf0
    __syncthreads();      // only prologue drain that exposes latency

    f32x4 O[8];
    #pragma unroll
    for (int di = 0; di < 8; ++di) O[di] = f32x4{0.f, 0.f, 0.f, 0.f};
    float m_prev[4] = {-INFINITY, -INFINITY, -INFINITY, -INFINITY};
    float l_run[4] = {0.f, 0.f, 0.f, 0.f};
    const int qrow_base = r0 + 16 * w + quad * 4;

    for (int j0 = 0; j0 < Sn; j0 += 64) {
        const int bb = ((j0 >> 6) & 1) * 24576;   // current buffer base
        const int nb = bb ^ 24576;                // next buffer base

        float mv[4][4];                        // bf16 mask prefetch (pre-scaled)
        #pragma unroll
        for (int ni = 0; ni < 4; ++ni)
            #pragma unroll
            for (int reg = 0; reg < 4; ++reg)
                mv[ni][reg] = bf2f(maskB[(size_t)(qrow_base + reg) * Sn + j0 + ni * 16 + l15]);

        if (j0 + 64 < Sn) STAGE(nb, j0 + 64);  // prefetch next tile (drained at end-of-iter barrier)

        // ---- QK^T (3 split products) from buf[bb] ----
        f32x4 p[4];
        #pragma unroll
        for (int ni = 0; ni < 4; ++ni) p[ni] = f32x4{0.f, 0.f, 0.f, 0.f};
        #pragma unroll
        for (int ni = 0; ni < 4; ++ni) {
            int col = ni * 16 + l15;
            #pragma unroll
            for (int kc = 0; kc < 4; ++kc) {
                int gp = (kc * 4 + quad) ^ (col & 7);
                short8 kh = *(const short8*)&lds0[bb + col * 128 + gp * 8];
                short8 kl = *(const short8*)&lds0[bb + 8192 + col * 128 + gp * 8];
                p[ni] = __builtin_amdgcn_mfma_f32_16x16x32_bf16(qh[kc], kh, p[ni], 0, 0, 0);
                p[ni] = __builtin_amdgcn_mfma_f32_16x16x32_bf16(qh[kc], kl, p[ni], 0, 0, 0);
                p[ni] = __builtin_amdgcn_mfma_f32_16x16x32_bf16(ql[kc], kh, p[ni], 0, 0, 0);
            }
        }

        // ---- softmax in base 2, DPP reductions (flash5 math, unchanged) ----
        float rm[4] = {-INFINITY, -INFINITY, -INFINITY, -INFINITY};
        #pragma unroll
        for (int ni = 0; ni < 4; ++ni)
            #pragma unroll
            for (int reg = 0; reg < 4; ++reg) {
                float v = fmaf(p[ni][reg], NORMS2, mv[ni][reg]);
                p[ni][reg] = v;
                rm[reg] = fmaxf(rm[reg], v);
            }
        #pragma unroll
        for (int reg = 0; reg < 4; ++reg) rm[reg] = redmax16(rm[reg]);
        float al[4], mn[4], rs[4];
        #pragma unroll
        for (int reg = 0; reg < 4; ++reg) {
            mn[reg] = fmaxf(m_prev[reg], rm[reg]);
            al[reg] = EXP2(m_prev[reg] - mn[reg]);
            rs[reg] = 0.f;
        }
        #pragma unroll
        for (int ni = 0; ni < 4; ++ni)
            #pragma unroll
            for (int reg = 0; reg < 4; ++reg) {
                float pe = EXP2(p[ni][reg] - mn[reg]);
                rs[reg] += pe;
                lds0[psb + (quad * 4 + reg) * 80 + ((ni ^ quad) << 4) + l15] = f2bf(pe);
            }
        #pragma unroll
        for (int reg = 0; reg < 4; ++reg) rs[reg] = redsum16(rs[reg]);
        #pragma unroll
        for (int reg = 0; reg < 4; ++reg) {
            l_run[reg] = l_run[reg] * al[reg] + rs[reg];
            m_prev[reg] = mn[reg];
        }
        #pragma unroll
        for (int di = 0; di < 8; ++di)
            #pragma unroll
            for (int reg = 0; reg < 4; ++reg)
                O[di][reg] *= al[reg];

        short8 pa[2];
        #pragma unroll
        for (int kc2 = 0; kc2 < 2; ++kc2) {
            int g = kc2 * 2 + (quad >> 1);
            int gs = g ^ (l15 >> 2);
            pa[kc2] = *(const short8*)&lds0[psb + l15 * 80 + (gs << 4) + (quad & 1) * 8];
        }

        // ---- PV from buf[bb] ----
        #pragma unroll
        for (int di = 0; di < 8; ++di) {
            int d = di * 16 + l15;
            #pragma unroll
            for (int kc2 = 0; kc2 < 2; ++kc2) {
                int gp = (kc2 * 4 + quad) ^ (d & 7);
                short8 vb = *(const short8*)&lds0[bb + 16384 + d * 64 + gp * 8];
                O[di] = __builtin_amdgcn_mfma_f32_16x16x32_bf16(pa[kc2], vb, O[di], 0, 0, 0);
            }
        }

        // ONE barrier per tile: prev-iter prefetch now visible to all waves,
        // and buf[bb] is free to be overwritten next iteration.
        __syncthreads();
    }

    float inv[4];
    #pragma unroll
    for (int reg = 0; reg < 4; ++reg) inv[reg] = 1.0f / l_run[reg];
    #pragma unroll
    for (int di = 0; di < 8; ++di)
        #pragma unroll
        for (int reg = 0; reg < 4; ++reg) {
            size_t idx = ((size_t)b * Sn + qrow_base + reg) * En + h * HDn + di * 16 + l15;
            AO[idx] = f2bf(O[di][reg] * inv[reg]);
        }
}

extern "C" void kernel_launch(void* const* d_in, const int* in_sizes, int n_in,
                              void* d_out, int out_size, void* d_ws, size_t ws_size,
                              hipStream_t stream) {
    const float* inputs = (const float*)d_in[0];
    const float* mask   = (const float*)d_in[1];
    const float* wq     = (const float*)d_in[2];
    const float* wk     = (const float*)d_in[3];
    const float* wv     = (const float*)d_in[4];
    const float* wo     = (const float*)d_in[5];
    float* out = (float*)d_out;
    (void)in_sizes; (void)n_in; (void)out_size; (void)ws_size;

    char* W8 = (char*)d_ws;
    float* sinT  = (float*)(W8 + 0);
    float* cosT  = (float*)(W8 + 524288);
    short* Xhi   = (short*)(W8 + 1048576);
    short* Xlo   = (short*)(W8 + 17825792);
    short* maskB = (short*)(W8 + 34603008);
    short* WqkTh = (short*)(W8 + 42991616);
    short* WqkTl = (short*)(W8 + 59768832);
    short* WvT   = (short*)(W8 + 76546048);
    short* WoT   = (short*)(W8 + 84934656);
    int*   Qpk   = (int*)(W8 + 93323264);
    int*   Kpk   = (int*)(W8 + 126877696);
    // aliases (lifetimes disjoint; ordering enforced by dispatch sequence):
    short* Qhi = WqkTh;                        // rope-Q out over W-qk (dead after QK-GEMM)
    short* Qlo = WqkTl;
    short* Khi = (short*)(W8 + 93323264);      // rope-K out over Qpk (dead after rope-Q)
    short* Klo = (short*)(W8 + 110100480);
    short* Vt  = (short*)(W8 + 126877696);     // V^T over Kpk (dead after rope-K)
    short* AO  = Xhi;                          // flash out over X-hi (dead after V-GEMM)

    rope_table_kernel<<<512, 256, 0, stream>>>(sinT, cosT);
    split_x_kernel<<<8192, 256, 0, stream>>>(inputs, Xhi, Xlo);
    maskconv_kernel<<<4096, 256, 0, stream>>>(mask, maskB);
    wtrans4_kernel<<<dim3(64, 64, 4), 256, 0, stream>>>(wq, wk, wv, wo,
                                                        WqkTh, WqkTl, WvT, WoT);

    gemm_kernel<3, 3><<<dim3(32, 32), 256, 0, stream>>>(
        Xhi, Xlo, WqkTh, WqkTl, nullptr, nullptr, Qpk, Kpk);
    rope_pk_kernel<<<8192, 256, 0, stream>>>(Qpk, Qhi, Qlo, sinT, cosT);
    rope_pk_kernel<<<8192, 256, 0, stream>>>(Kpk, Khi, Klo, sinT, cosT);
    gemm_kernel<1, 1><<<dim3(16, 32), 256, 0, stream>>>(
        Xhi, nullptr, WvT, nullptr, nullptr, Vt, nullptr, nullptr);

    flash9_kernel<<<512, 512, 0, stream>>>(Qhi, Qlo, Khi, Klo, Vt, maskB, AO);

    gemm_kernel<1, 0><<<dim3(16, 32), 256, 0, stream>>>(
        AO, nullptr, WoT, nullptr, out, nullptr, nullptr, nullptr);
}

// Round 8
// 620.018 us; speedup vs baseline: 1.2103x; 1.0455x over previous
//
#include <hip/hip_runtime.h>
#include <hip/hip_bf16.h>
#include <cmath>

#define Bn 2
#define Sn 2048
#define En 2048
#define Hn 16
#define HDn 128
#define Mn (Bn*Sn)
#define NORMS2 92.33248261689366f   /* 64 * log2(e) : softmax done in base 2 */

typedef __attribute__((ext_vector_type(8))) short short8;
typedef __attribute__((ext_vector_type(4))) float f32x4;

__device__ __forceinline__ short f2bf(float x) {
    __hip_bfloat16 h = __float2bfloat16(x);
    return *reinterpret_cast<short*>(&h);
}
__device__ __forceinline__ float bf2f(short s) {
    __hip_bfloat16 h = *reinterpret_cast<__hip_bfloat16*>(&s);
    return __bfloat162float(h);
}
__device__ __forceinline__ void gl_lds16(const void* g, void* l) {
    __builtin_amdgcn_global_load_lds(
        (const __attribute__((address_space(1))) unsigned int*)g,
        (__attribute__((address_space(3))) unsigned int*)l, 16, 0, 0);
}

#if __has_builtin(__builtin_amdgcn_exp2f)
#define EXP2(x) __builtin_amdgcn_exp2f(x)
#else
#define EXP2(x) exp2f(x)
#endif

template<int CTRL>
__device__ __forceinline__ float dppf(float x) {
    int r = __builtin_amdgcn_update_dpp(0, __builtin_bit_cast(int, x), CTRL, 0xf, 0xf, true);
    return __builtin_bit_cast(float, r);
}
__device__ __forceinline__ float redmax16(float x) {
    x = fmaxf(x, dppf<0xB1>(x));   // quad_perm xor1
    x = fmaxf(x, dppf<0x4E>(x));   // quad_perm xor2
    x = fmaxf(x, dppf<0x141>(x));  // row_half_mirror xor7
    x = fmaxf(x, dppf<0x140>(x));  // row_mirror xor15
    return x;
}
__device__ __forceinline__ float redsum16(float x) {
    x += dppf<0xB1>(x);
    x += dppf<0x4E>(x);
    x += dppf<0x141>(x);
    x += dppf<0x140>(x);
    return x;
}

// ---- sin/cos tables in fp64 ----
static __global__ void rope_table_kernel(float* __restrict__ sinT, float* __restrict__ cosT) {
    int i = blockIdx.x * 256 + threadIdx.x;
    int t = i >> 6, f = i & 63;
    double inv = pow(10000.0, -(double)(2 * f) / (double)HDn);
    double ang = (double)t * inv;
    sinT[i] = (float)sin(ang);
    cosT[i] = (float)cos(ang);
}

// ---- split fp32 -> bf16 hi/lo ----
static __global__ void split_x_kernel(const float* __restrict__ X,
                                      short* __restrict__ Xhi, short* __restrict__ Xlo) {
    int i = (blockIdx.x * 256 + threadIdx.x) * 4;
    float4 x = *(const float4*)&X[i];
    short4 hi, lo;
    hi.x = f2bf(x.x); lo.x = f2bf(x.x - bf2f(hi.x));
    hi.y = f2bf(x.y); lo.y = f2bf(x.y - bf2f(hi.y));
    hi.z = f2bf(x.z); lo.z = f2bf(x.z - bf2f(hi.z));
    hi.w = f2bf(x.w); lo.w = f2bf(x.w - bf2f(hi.w));
    *(short4*)&Xhi[i] = hi;
    *(short4*)&Xlo[i] = lo;
}

// ---- mask fp32 -> bf16, pre-scaled by NORMS2 (exact for zero mask) ----
static __global__ void maskconv_kernel(const float* __restrict__ M, short* __restrict__ MB) {
    int i = (blockIdx.x * 256 + threadIdx.x) * 4;
    float4 m = *(const float4*)&M[i];
    short4 o;
    o.x = f2bf(m.x * NORMS2); o.y = f2bf(m.y * NORMS2);
    o.z = f2bf(m.z * NORMS2); o.w = f2bf(m.w * NORMS2);
    *(short4*)&MB[i] = o;
}

// ---- transpose all 4 weights in one dispatch (z selects) ----
static __global__ __launch_bounds__(256) void wtrans4_kernel(
        const float* __restrict__ Wq, const float* __restrict__ Wk,
        const float* __restrict__ Wv, const float* __restrict__ Wo,
        short* __restrict__ QKh, short* __restrict__ QKl,
        short* __restrict__ VT, short* __restrict__ OT) {
    __shared__ float tile[32][33];
    const int z = blockIdx.z;
    const float* W = (z == 0) ? Wq : (z == 1) ? Wk : (z == 2) ? Wv : Wo;
    short* Th = (z <= 1) ? QKh : (z == 2) ? VT : OT;
    const int rowoff = (z == 1) ? 2048 : 0;
    const bool split = (z <= 1);
    int tx = threadIdx.x & 31, ty = threadIdx.x >> 5;
    int k0 = blockIdx.y * 32, n0 = blockIdx.x * 32;
    #pragma unroll
    for (int i = 0; i < 4; ++i)
        tile[ty + i * 8][tx] = W[(size_t)(k0 + ty + i * 8) * En + n0 + tx];
    __syncthreads();
    #pragma unroll
    for (int i = 0; i < 4; ++i) {
        float v = tile[tx][ty + i * 8];
        size_t idx = (size_t)(rowoff + n0 + ty + i * 8) * En + k0 + tx;
        short hv = f2bf(v);
        Th[idx] = hv;
        if (split) QKl[idx] = f2bf(v - bf2f(hv));
    }
}

// ---- 256x256-tile QKV GEMM (NPROD=3, packed OUTMODE=3), BK=32 ----
// R7: per-wave tile 128x64 (8 waves, 2x4) quadruples A-fragment reuse ->
// LDS reads drop from 48 to 64 FLOP/B; per-K-step LDS (~2260cyc) < MFMA
// (~3090cyc), so MFMA finally dominates. Keeps R5 counted-vmcnt + R6 T2
// swizzle (verified formulas, ranges extended). LDS 128KB dbuf, 1 block/CU
// (8 waves/CU -- same occupancy as 2x 128^2 blocks).
static __global__ __launch_bounds__(512, 2) void gemm256_kernel(
        const short* __restrict__ Ahi, const short* __restrict__ Alo,
        const short* __restrict__ Bhi, const short* __restrict__ Blo,
        int* __restrict__ Qpk, int* __restrict__ Kpk) {
    __shared__ short As_hi[2 * 256 * 32];
    __shared__ short As_lo[2 * 256 * 32];
    __shared__ short Bs_hi[2 * 256 * 32];
    __shared__ short Bs_lo[2 * 256 * 32];

    const int tid = threadIdx.x;
    const int w = tid >> 6, l = tid & 63;
    const int quad = l >> 4, l15 = l & 15;
    const int wr = (w >> 2) * 128, wc = (w & 3) * 64;   // 2x4 wave grid
    const int row0 = blockIdx.y * 256, col0 = blockIdx.x * 256;

    const int off0 = tid * 16;                  // bytes in [0,8192)
    const int r_a = off0 >> 6;                  // staging row 0..127 (and +128)
    const int slot = (off0 >> 4) & 3;
    // T2 pre-swizzle; (r_a>>1)&3 invariant under row+128 (128/2 % 4 == 0)
    const int kb = (slot ^ ((r_a >> 1) & 3)) * 8;   // shorts

    // stage one 256x32 K-tile (4 planes) into buffer at short-offset bs
    // 8 gl_lds16 per thread per call.
    auto STAGE = [&](int bs, int kk) {
        const short* ap  = Ahi + (size_t)(row0 + r_a) * En + kk + kb;
        const short* bp  = Bhi + (size_t)(col0 + r_a) * En + kk + kb;
        const short* ap2 = Alo + (size_t)(row0 + r_a) * En + kk + kb;
        const short* bp2 = Blo + (size_t)(col0 + r_a) * En + kk + kb;
        gl_lds16(ap,            &As_hi[bs + off0 / 2]);
        gl_lds16(ap + 128 * En, &As_hi[bs + (off0 + 8192) / 2]);
        gl_lds16(bp,            &Bs_hi[bs + off0 / 2]);
        gl_lds16(bp + 128 * En, &Bs_hi[bs + (off0 + 8192) / 2]);
        gl_lds16(ap2,            &As_lo[bs + off0 / 2]);
        gl_lds16(ap2 + 128 * En, &As_lo[bs + (off0 + 8192) / 2]);
        gl_lds16(bp2,            &Bs_lo[bs + off0 / 2]);
        gl_lds16(bp2 + 128 * En, &Bs_lo[bs + (off0 + 8192) / 2]);
    };

    f32x4 acc[8][4];
    #pragma unroll
    for (int i = 0; i < 8; ++i)
        #pragma unroll
        for (int j = 0; j < 4; ++j) acc[i][j] = f32x4{0.f, 0.f, 0.f, 0.f};

    STAGE(0, 0);
    __syncthreads();   // prologue: full drain once (tile 0 visible)

    for (int k0 = 0; k0 < En; k0 += 32) {
        const int cb = ((k0 >> 5) & 1) * 8192;   // current buffer (shorts)
        const int nb = cb ^ 8192;                // next buffer
        if (k0 + 32 < En) {
            STAGE(nb, k0 + 32);                  // prefetch stays in flight
            asm volatile("s_waitcnt vmcnt(8)" ::: "memory");  // wait prev iter only
        } else {
            asm volatile("s_waitcnt vmcnt(0)" ::: "memory");  // last tile: drain
        }
        __builtin_amdgcn_sched_barrier(0);       // rule #18: pin order
        __builtin_amdgcn_s_barrier();            // all waves' cb loads complete

        short8 bhf[4], blf[4];
        #pragma unroll
        for (int ni = 0; ni < 4; ++ni) {
            int br = wc + ni * 16 + l15;
            int bsw = (quad ^ ((br >> 1) & 3)) * 8;
            bhf[ni] = *(const short8*)&Bs_hi[cb + br * 32 + bsw];
            blf[ni] = *(const short8*)&Bs_lo[cb + br * 32 + bsw];
        }
        #pragma unroll
        for (int mi = 0; mi < 8; ++mi) {
            int ar = wr + mi * 16 + l15;
            int asw = (quad ^ ((ar >> 1) & 3)) * 8;
            short8 ahf = *(const short8*)&As_hi[cb + ar * 32 + asw];
            short8 alf = *(const short8*)&As_lo[cb + ar * 32 + asw];
            #pragma unroll
            for (int ni = 0; ni < 4; ++ni) {
                acc[mi][ni] = __builtin_amdgcn_mfma_f32_16x16x32_bf16(ahf, bhf[ni], acc[mi][ni], 0, 0, 0);
                acc[mi][ni] = __builtin_amdgcn_mfma_f32_16x16x32_bf16(ahf, blf[ni], acc[mi][ni], 0, 0, 0);
                acc[mi][ni] = __builtin_amdgcn_mfma_f32_16x16x32_bf16(alf, bhf[ni], acc[mi][ni], 0, 0, 0);
            }
        }
        // bare barrier (no vmcnt drain): all cb ds_reads consumed above.
        __builtin_amdgcn_s_barrier();
    }

    int* dst = (col0 >= 2048) ? Kpk : Qpk;
    const int cbase = col0 & 2047;
    #pragma unroll
    for (int mi = 0; mi < 8; ++mi)
        #pragma unroll
        for (int ni = 0; ni < 4; ++ni) {
            int r = row0 + wr + mi * 16 + quad * 4;
            int c = cbase + wc + ni * 16 + l15;
            #pragma unroll
            for (int reg = 0; reg < 4; ++reg) {
                float v = acc[mi][ni][reg];
                short hh = f2bf(v);
                short ll = f2bf(v - bf2f(hh));
                dst[(size_t)(r + reg) * 2048 + c] =
                    ((int)(unsigned short)hh << 16) | (unsigned short)ll;
            }
        }
}

// ---- MFMA GEMM: C[M][N] = A[M][K] * BT[N][K]^T, 128x128 tile, BK=32 ----
// (now used for the NPROD=1 paths only; keeps dbuf + counted vmcnt + T2)
// OUTMODE=0: fp32 row-major -> Cf
// OUTMODE=1: bf16 V^T [(b,h,d)][s] via LDS transpose (coalesced) -> Cbt
template<int NPROD, int OUTMODE>
static __global__ __launch_bounds__(256) void gemm_kernel(
        const short* __restrict__ Ahi, const short* __restrict__ Alo,
        const short* __restrict__ Bhi, const short* __restrict__ Blo,
        float* __restrict__ Cf, short* __restrict__ Cbt,
        int* __restrict__ Qpk, int* __restrict__ Kpk) {
    __shared__ short As_hi[2 * 128 * 32];
    __shared__ short Bs_hi[2 * 128 * 32];
    __shared__ short As_lo[NPROD == 3 ? 2 * 128 * 32 : 8];
    __shared__ short Bs_lo[NPROD == 3 ? 2 * 128 * 32 : 8];
    __shared__ short Ts[OUTMODE == 1 ? 128 * 136 : 8];

    const int tid = threadIdx.x;
    const int w = tid >> 6, l = tid & 63;
    const int quad = l >> 4, l15 = l & 15;
    const int wr = (w >> 1) * 64, wc = (w & 1) * 64;
    const int row0 = blockIdx.y * 128, col0 = blockIdx.x * 128;

    const int off0 = tid * 16;
    const int r_a = off0 >> 6;
    const int slot = (off0 >> 4) & 3;
    const int kb = (slot ^ ((r_a >> 1) & 3)) * 8;   // shorts (T2 pre-swizzle)

    auto STAGE = [&](int bs, int kk) {
        const short* ap = Ahi + (size_t)(row0 + r_a) * En + kk + kb;
        const short* bp = Bhi + (size_t)(col0 + r_a) * En + kk + kb;
        gl_lds16(ap,           &As_hi[bs + off0 / 2]);
        gl_lds16(ap + 64 * En, &As_hi[bs + (off0 + 4096) / 2]);
        gl_lds16(bp,           &Bs_hi[bs + off0 / 2]);
        gl_lds16(bp + 64 * En, &Bs_hi[bs + (off0 + 4096) / 2]);
        if constexpr (NPROD == 3) {
            const short* ap2 = Alo + (size_t)(row0 + r_a) * En + kk + kb;
            const short* bp2 = Blo + (size_t)(col0 + r_a) * En + kk + kb;
            gl_lds16(ap2,           &As_lo[bs + off0 / 2]);
            gl_lds16(ap2 + 64 * En, &As_lo[bs + (off0 + 4096) / 2]);
            gl_lds16(bp2,           &Bs_lo[bs + off0 / 2]);
            gl_lds16(bp2 + 64 * En, &Bs_lo[bs + (off0 + 4096) / 2]);
        }
    };

    f32x4 acc[4][4];
    #pragma unroll
    for (int i = 0; i < 4; ++i)
        #pragma unroll
        for (int j = 0; j < 4; ++j) acc[i][j] = f32x4{0.f, 0.f, 0.f, 0.f};

    STAGE(0, 0);
    __syncthreads();   // prologue: full drain once

    for (int k0 = 0; k0 < En; k0 += 32) {
        const int cb = ((k0 >> 5) & 1) * 4096;
        const int nb = cb ^ 4096;
        if (k0 + 32 < En) {
            STAGE(nb, k0 + 32);
            asm volatile("s_waitcnt vmcnt(%0)" :: "i"(NPROD == 3 ? 8 : 4) : "memory");
        } else {
            asm volatile("s_waitcnt vmcnt(0)" ::: "memory");
        }
        __builtin_amdgcn_sched_barrier(0);
        __builtin_amdgcn_s_barrier();

        short8 bhf[4], blf[4];
        #pragma unroll
        for (int ni = 0; ni < 4; ++ni) {
            int br = wc + ni * 16 + l15;
            int bsw = (quad ^ ((br >> 1) & 3)) * 8;
            bhf[ni] = *(const short8*)&Bs_hi[cb + br * 32 + bsw];
            if constexpr (NPROD == 3)
                blf[ni] = *(const short8*)&Bs_lo[cb + br * 32 + bsw];
        }
        #pragma unroll
        for (int mi = 0; mi < 4; ++mi) {
            int ar = wr + mi * 16 + l15;
            int asw = (quad ^ ((ar >> 1) & 3)) * 8;
            short8 ahf = *(const short8*)&As_hi[cb + ar * 32 + asw];
            short8 alf;
            if constexpr (NPROD == 3)
                alf = *(const short8*)&As_lo[cb + ar * 32 + asw];
            #pragma unroll
            for (int ni = 0; ni < 4; ++ni) {
                acc[mi][ni] = __builtin_amdgcn_mfma_f32_16x16x32_bf16(ahf, bhf[ni], acc[mi][ni], 0, 0, 0);
                if constexpr (NPROD == 3) {
                    acc[mi][ni] = __builtin_amdgcn_mfma_f32_16x16x32_bf16(ahf, blf[ni], acc[mi][ni], 0, 0, 0);
                    acc[mi][ni] = __builtin_amdgcn_mfma_f32_16x16x32_bf16(alf, bhf[ni], acc[mi][ni], 0, 0, 0);
                }
            }
        }
        __builtin_amdgcn_s_barrier();
    }

    if constexpr (OUTMODE == 0) {
        #pragma unroll
        for (int mi = 0; mi < 4; ++mi)
            #pragma unroll
            for (int ni = 0; ni < 4; ++ni) {
                int r = row0 + wr + mi * 16 + quad * 4;
                int c = col0 + wc + ni * 16 + l15;
                #pragma unroll
                for (int reg = 0; reg < 4; ++reg)
                    Cf[(size_t)(r + reg) * En + c] = acc[mi][ni][reg];
            }
    } else if constexpr (OUTMODE == 1) {
        // LDS transpose -> coalesced V^T stores
        #pragma unroll
        for (int mi = 0; mi < 4; ++mi)
            #pragma unroll
            for (int ni = 0; ni < 4; ++ni) {
                int dl = wc + ni * 16 + l15;            // local col (d)
                int sl = wr + mi * 16 + quad * 4;       // local row (s)
                #pragma unroll
                for (int reg = 0; reg < 4; ++reg)
                    Ts[dl * 136 + sl + reg] = f2bf(acc[mi][ni][reg]);
            }
        __syncthreads();
        int dl = tid >> 1, s0 = (tid & 1) * 64;
        int b = row0 >> 11, h = col0 >> 7;
        size_t gbase = ((size_t)(b * Hn + h) * HDn + dl) * Sn + (row0 & (Sn - 1)) + s0;
        #pragma unroll
        for (int k = 0; k < 8; ++k) {
            short8 vv = *(const short8*)&Ts[dl * 136 + s0 + k * 8];
            *(short8*)&Cbt[gbase + k * 8] = vv;
        }
    } else {
        int* dst = (col0 >= 2048) ? Kpk : Qpk;
        const int cbx = col0 & 2047;
        #pragma unroll
        for (int mi = 0; mi < 4; ++mi)
            #pragma unroll
            for (int ni = 0; ni < 4; ++ni) {
                int r = row0 + wr + mi * 16 + quad * 4;
                int c = cbx + wc + ni * 16 + l15;
                #pragma unroll
                for (int reg = 0; reg < 4; ++reg) {
                    float v = acc[mi][ni][reg];
                    short hh = f2bf(v);
                    short ll = f2bf(v - bf2f(hh));
                    dst[(size_t)(r + reg) * 2048 + c] =
                        ((int)(unsigned short)hh << 16) | (unsigned short)ll;
                }
            }
    }
}

// ---- RoPE on packed (hi<<16|lo) int32 -> split bf16 planes ----
static __global__ void rope_pk_kernel(const int* __restrict__ Pre,
        short* __restrict__ Yh, short* __restrict__ Yl,
        const float* __restrict__ sinT, const float* __restrict__ cosT) {
    int p = blockIdx.x * 256 + threadIdx.x;       // < 2^21 ; 4 elements/thread
    int u = p & 511;
    int t = (p >> 9) & (Sn - 1);
    int b = p >> 20;
    int tsrc; float sgn;
    if (t < Sn / 2) { tsrc = 2 * t + 1; sgn = -1.f; }
    else            { tsrc = 2 * (t - Sn / 2); sgn = 1.f; }
    int f0 = (2 * u) & 63, f1 = (2 * u + 1) & 63;
    float sv0 = sinT[(t << 6) + f0], cv0 = cosT[(t << 6) + f0];
    float sv1 = sinT[(t << 6) + f1], cv1 = cosT[(t << 6) + f1];
    size_t rt = ((size_t)(b * Sn + t)) * 512 + u;     // int4 units
    size_t rs = ((size_t)(b * Sn + tsrc)) * 512 + u;
    int4 xt = ((const int4*)Pre)[rt];
    int4 xs = ((const int4*)Pre)[rs];
    auto up = [](int v) -> float {
        return bf2f((short)(v >> 16)) + bf2f((short)(v & 0xffff));
    };
    float x0 = up(xt.x), x1 = up(xt.y), x2 = up(xt.z), x3 = up(xt.w);
    float s0 = up(xs.x), s1 = up(xs.y), s2 = up(xs.z), s3 = up(xs.w);
    float y0 = x0 * cv0 + sgn * s0 * sv0;
    float y1 = x1 * cv0 + sgn * s1 * sv0;
    float y2 = x2 * cv1 + sgn * s2 * sv1;
    float y3 = x3 * cv1 + sgn * s3 * sv1;
    short4 hi, lo;
    hi.x = f2bf(y0); lo.x = f2bf(y0 - bf2f(hi.x));
    hi.y = f2bf(y1); lo.y = f2bf(y1 - bf2f(hi.y));
    hi.z = f2bf(y2); lo.z = f2bf(y2 - bf2f(hi.z));
    hi.w = f2bf(y3); lo.w = f2bf(y3 - bf2f(hi.w));
    size_t o = ((size_t)(b * Sn + t)) * En + 4 * u;
    *(short4*)&Yh[o] = hi;
    *(short4*)&Yl[o] = lo;
}

// ---- MFMA flash attention v9 ----
// 512 threads (8 waves), 128 q-rows/block, 64-key tiles; flash5 per-tile
// compute (identical numerics) + K/V LDS DOUBLE-BUFFER with stage-early /
// drain-late: stage tile j+1 into buf^1 at top of iter, compute tile j from
// buf, ONE __syncthreads per tile at the END.
// LDS (shorts): buf0 [0,24576): K-hi/K-lo/V each 8192
//               buf1 [24576,49152): same layout
//               P    [49152,59392): 8 waves x 1280
// Q staged transiently in [0,32768) before buffers are first used.
// 118784 B -> 1 block/CU (8 waves).
static __global__ __launch_bounds__(512, 2) void flash9_kernel(
        const short* __restrict__ Qhi, const short* __restrict__ Qlo,
        const short* __restrict__ Khi, const short* __restrict__ Klo,
        const short* __restrict__ Vt, const short* __restrict__ maskB,
        short* __restrict__ AO) {
    __shared__ short lds0[59392];

    const int tid = threadIdx.x;
    const int w = tid >> 6, l = tid & 63;
    const int quad = l >> 4, l15 = l & 15;
    const int n = blockIdx.x;
    const int bh = (n & 7) * 4 + ((n >> 3) & 3);   // heads grouped per XCD
    const int qt = n >> 5;                          // 32 consecutive blocks share mask rows
    const int b = bh >> 4, h = bh & 15;
    const int r0 = qt * 128;
    const size_t qkbase = (size_t)b * Sn * En + (size_t)h * HDn;
    const int psb = 49152 + w * 1280;

    // ---- stage Q (transient, overlaps buffer region) ----
    #pragma unroll
    for (int c = 0; c < 4; ++c) {
        int off = tid * 16 + c * 8192;
        int row = off >> 8;
        int gp = (off >> 4) & 15;
        int gl = gp ^ (row & 7);
        size_t gidx = qkbase + (size_t)(r0 + row) * En + gl * 8;
        gl_lds16(Qhi + gidx, &lds0[off / 2]);
        gl_lds16(Qlo + gidx, &lds0[16384 + off / 2]);
    }
    __syncthreads();
    short8 qh[4], ql[4];
    {
        int row = 16 * w + l15;
        #pragma unroll
        for (int kc = 0; kc < 4; ++kc) {
            int gp = (kc * 4 + quad) ^ (row & 7);
            qh[kc] = *(const short8*)&lds0[row * 128 + gp * 8];
            ql[kc] = *(const short8*)&lds0[16384 + row * 128 + gp * 8];
        }
    }
    __syncthreads();   // all waves done reading Q before buffers are written

    // ---- staging helper: K hi/lo + V for key-tile jj into buffer at bbase ----
    auto STAGE = [&](int bbase, int jj) {
        #pragma unroll
        for (int c = 0; c < 2; ++c) {          // K hi/lo (64 rows x 256 B)
            int off = tid * 16 + c * 8192;     // [0,16384) bytes
            int row = off >> 8;                // 0..63
            int gp = (off >> 4) & 15;
            int gl = gp ^ (row & 7);
            size_t gidx = qkbase + (size_t)(jj + row) * En + gl * 8;
            gl_lds16(Khi + gidx, &lds0[bbase + off / 2]);
            gl_lds16(Klo + gidx, &lds0[bbase + 8192 + off / 2]);
        }
        #pragma unroll
        for (int c = 0; c < 2; ++c) {          // V (128 d-rows x 128 B)
            int off = tid * 16 + c * 8192;     // [0,16384) bytes
            int vrow = off >> 7;               // 0..127
            int vgp = (off >> 4) & 7;
            int vgl = vgp ^ (vrow & 7);
            size_t vidx = ((size_t)bh * HDn + vrow) * Sn + jj + vgl * 8;
            gl_lds16(Vt + vidx, &lds0[bbase + 16384 + off / 2]);
        }
    };

    STAGE(0, 0);          // tile 0 -> buf0
    __syncthreads();      // only prologue drain that exposes latency

    f32x4 O[8];
    #pragma unroll
    for (int di = 0; di < 8; ++di) O[di] = f32x4{0.f, 0.f, 0.f, 0.f};
    float m_prev[4] = {-INFINITY, -INFINITY, -INFINITY, -INFINITY};
    float l_run[4] = {0.f, 0.f, 0.f, 0.f};
    const int qrow_base = r0 + 16 * w + quad * 4;

    for (int j0 = 0; j0 < Sn; j0 += 64) {
        const int bb = ((j0 >> 6) & 1) * 24576;   // current buffer base
        const int nb = bb ^ 24576;                // next buffer base

        float mv[4][4];                        // bf16 mask prefetch (pre-scaled)
        #pragma unroll
        for (int ni = 0; ni < 4; ++ni)
            #pragma unroll
            for (int reg = 0; reg < 4; ++reg)
                mv[ni][reg] = bf2f(maskB[(size_t)(qrow_base + reg) * Sn + j0 + ni * 16 + l15]);

        if (j0 + 64 < Sn) STAGE(nb, j0 + 64);  // prefetch next tile (drained at end-of-iter barrier)

        // ---- QK^T (3 split products) from buf[bb] ----
        f32x4 p[4];
        #pragma unroll
        for (int ni = 0; ni < 4; ++ni) p[ni] = f32x4{0.f, 0.f, 0.f, 0.f};
        #pragma unroll
        for (int ni = 0; ni < 4; ++ni) {
            int col = ni * 16 + l15;
            #pragma unroll
            for (int kc = 0; kc < 4; ++kc) {
                int gp = (kc * 4 + quad) ^ (col & 7);
                short8 kh = *(const short8*)&lds0[bb + col * 128 + gp * 8];
                short8 kl = *(const short8*)&lds0[bb + 8192 + col * 128 + gp * 8];
                p[ni] = __builtin_amdgcn_mfma_f32_16x16x32_bf16(qh[kc], kh, p[ni], 0, 0, 0);
                p[ni] = __builtin_amdgcn_mfma_f32_16x16x32_bf16(qh[kc], kl, p[ni], 0, 0, 0);
                p[ni] = __builtin_amdgcn_mfma_f32_16x16x32_bf16(ql[kc], kh, p[ni], 0, 0, 0);
            }
        }

        // ---- softmax in base 2, DPP reductions (flash5 math, unchanged) ----
        float rm[4] = {-INFINITY, -INFINITY, -INFINITY, -INFINITY};
        #pragma unroll
        for (int ni = 0; ni < 4; ++ni)
            #pragma unroll
            for (int reg = 0; reg < 4; ++reg) {
                float v = fmaf(p[ni][reg], NORMS2, mv[ni][reg]);
                p[ni][reg] = v;
                rm[reg] = fmaxf(rm[reg], v);
            }
        #pragma unroll
        for (int reg = 0; reg < 4; ++reg) rm[reg] = redmax16(rm[reg]);
        float al[4], mn[4], rs[4];
        #pragma unroll
        for (int reg = 0; reg < 4; ++reg) {
            mn[reg] = fmaxf(m_prev[reg], rm[reg]);
            al[reg] = EXP2(m_prev[reg] - mn[reg]);
            rs[reg] = 0.f;
        }
        #pragma unroll
        for (int ni = 0; ni < 4; ++ni)
            #pragma unroll
            for (int reg = 0; reg < 4; ++reg) {
                float pe = EXP2(p[ni][reg] - mn[reg]);
                rs[reg] += pe;
                lds0[psb + (quad * 4 + reg) * 80 + ((ni ^ quad) << 4) + l15] = f2bf(pe);
            }
        #pragma unroll
        for (int reg = 0; reg < 4; ++reg) rs[reg] = redsum16(rs[reg]);
        #pragma unroll
        for (int reg = 0; reg < 4; ++reg) {
            l_run[reg] = l_run[reg] * al[reg] + rs[reg];
            m_prev[reg] = mn[reg];
        }
        #pragma unroll
        for (int di = 0; di < 8; ++di)
            #pragma unroll
            for (int reg = 0; reg < 4; ++reg)
                O[di][reg] *= al[reg];

        short8 pa[2];
        #pragma unroll
        for (int kc2 = 0; kc2 < 2; ++kc2) {
            int g = kc2 * 2 + (quad >> 1);
            int gs = g ^ (l15 >> 2);
            pa[kc2] = *(const short8*)&lds0[psb + l15 * 80 + (gs << 4) + (quad & 1) * 8];
        }

        // ---- PV from buf[bb] ----
        #pragma unroll
        for (int di = 0; di < 8; ++di) {
            int d = di * 16 + l15;
            #pragma unroll
            for (int kc2 = 0; kc2 < 2; ++kc2) {
                int gp = (kc2 * 4 + quad) ^ (d & 7);
                short8 vb = *(const short8*)&lds0[bb + 16384 + d * 64 + gp * 8];
                O[di] = __builtin_amdgcn_mfma_f32_16x16x32_bf16(pa[kc2], vb, O[di], 0, 0, 0);
            }
        }

        // ONE barrier per tile: prev-iter prefetch now visible to all waves,
        // and buf[bb] is free to be overwritten next iteration.
        __syncthreads();
    }

    float inv[4];
    #pragma unroll
    for (int reg = 0; reg < 4; ++reg) inv[reg] = 1.0f / l_run[reg];
    #pragma unroll
    for (int di = 0; di < 8; ++di)
        #pragma unroll
        for (int reg = 0; reg < 4; ++reg) {
            size_t idx = ((size_t)b * Sn + qrow_base + reg) * En + h * HDn + di * 16 + l15;
            AO[idx] = f2bf(O[di][reg] * inv[reg]);
        }
}

extern "C" void kernel_launch(void* const* d_in, const int* in_sizes, int n_in,
                              void* d_out, int out_size, void* d_ws, size_t ws_size,
                              hipStream_t stream) {
    const float* inputs = (const float*)d_in[0];
    const float* mask   = (const float*)d_in[1];
    const float* wq     = (const float*)d_in[2];
    const float* wk     = (const float*)d_in[3];
    const float* wv     = (const float*)d_in[4];
    const float* wo     = (const float*)d_in[5];
    float* out = (float*)d_out;
    (void)in_sizes; (void)n_in; (void)out_size; (void)ws_size;

    char* W8 = (char*)d_ws;
    float* sinT  = (float*)(W8 + 0);
    float* cosT  = (float*)(W8 + 524288);
    short* Xhi   = (short*)(W8 + 1048576);
    short* Xlo   = (short*)(W8 + 17825792);
    short* maskB = (short*)(W8 + 34603008);
    short* WqkTh = (short*)(W8 + 42991616);
    short* WqkTl = (short*)(W8 + 59768832);
    short* WvT   = (short*)(W8 + 76546048);
    short* WoT   = (short*)(W8 + 84934656);
    int*   Qpk   = (int*)(W8 + 93323264);
    int*   Kpk   = (int*)(W8 + 126877696);
    // aliases (lifetimes disjoint; ordering enforced by dispatch sequence):
    short* Qhi = WqkTh;                        // rope-Q out over W-qk (dead after QK-GEMM)
    short* Qlo = WqkTl;
    short* Khi = (short*)(W8 + 93323264);      // rope-K out over Qpk (dead after rope-Q)
    short* Klo = (short*)(W8 + 110100480);
    short* Vt  = (short*)(W8 + 126877696);     // V^T over Kpk (dead after rope-K)
    short* AO  = Xhi;                          // flash out over X-hi (dead after V-GEMM)

    rope_table_kernel<<<512, 256, 0, stream>>>(sinT, cosT);
    split_x_kernel<<<8192, 256, 0, stream>>>(inputs, Xhi, Xlo);
    maskconv_kernel<<<4096, 256, 0, stream>>>(mask, maskB);
    wtrans4_kernel<<<dim3(64, 64, 4), 256, 0, stream>>>(wq, wk, wv, wo,
                                                        WqkTh, WqkTl, WvT, WoT);

    gemm256_kernel<<<dim3(16, 16), 512, 0, stream>>>(
        Xhi, Xlo, WqkTh, WqkTl, Qpk, Kpk);
    rope_pk_kernel<<<8192, 256, 0, stream>>>(Qpk, Qhi, Qlo, sinT, cosT);
    rope_pk_kernel<<<8192, 256, 0, stream>>>(Kpk, Khi, Klo, sinT, cosT);
    gemm_kernel<1, 1><<<dim3(16, 32), 256, 0, stream>>>(
        Xhi, nullptr, WvT, nullptr, nullptr, Vt, nullptr, nullptr);

    flash9_kernel<<<512, 512, 0, stream>>>(Qhi, Qlo, Khi, Klo, Vt, maskB, AO);

    gemm_kernel<1, 0><<<dim3(16, 32), 256, 0, stream>>>(
        AO, nullptr, WoT, nullptr, out, nullptr, nullptr, nullptr);
}